// Round 8
// baseline (2813.008 us; speedup 1.0000x reference)
//
#include <hip/hip_runtime.h>

#define NV   100000
#define NE   50000
#define NNZ  3200000
#define KIN  256
#define KOUT 64

#define NB    400                  // partition/hist blocks (NNZ = 400*8000 exactly)
#define CHUNK (NNZ / NB)           // 8000
#define NBE   782                  // ceil(NE/64) edge buckets
#define NBV   1563                 // ceil(NV/64) vertex buckets
#define NBINS (NBE + NBV)          // 2345
#define LSCAN (NBINS * NB)         // 938000
#define NBLK_SCAN ((LSCAN + 1023) / 1024)   // 917 (must stay <= 1024 for k_scan2)

#define PROWS 128                  // k_project tile rows
#define PKC   64                   // k_project K-chunk
#define XS_LD 68                   // Xs padded stride

__device__ __forceinline__ unsigned short f2bf(float f) {
    union { float f; unsigned u; } c{f};
    const unsigned lsb = (c.u >> 16) & 1u;
    return (unsigned short)((c.u + 0x7FFFu + lsb) >> 16);
}
__device__ __forceinline__ float bf2f(unsigned short h) {
    union { unsigned u; float f; } c{((unsigned)h) << 16};
    return c.f;
}

// ---------------------------------------------------------------------------
// Tiny one-off: Wt[k][o] = W[o][k]
// ---------------------------------------------------------------------------
__global__ __launch_bounds__(256) void k_wt(const float* __restrict__ W,
                                            float* __restrict__ Wt) {
    const int o = blockIdx.x;
    const int k = threadIdx.x;
    Wt[k * KOUT + o] = W[o * KIN + k];
}

// ---------------------------------------------------------------------------
// Kernel 1 (round-6 structure, bf16 output): Xp[r][o] = sum_k X[r][k]*W[o][k]
// ---------------------------------------------------------------------------
__global__ __launch_bounds__(256) void k_project(const float* __restrict__ X,
                                                 const float* __restrict__ Wt,
                                                 unsigned short* __restrict__ Xpb) {
    __shared__ float Xs[PROWS * XS_LD];   // 34.8 KB
    __shared__ float Ws[PKC * KOUT];      // 16 KB

    const int tid = threadIdx.x;
    const int rbase = blockIdx.x * PROWS;
    const int rg = tid >> 3;              // rows rg, rg+32, rg+64, rg+96
    const int c8 = (tid & 7) * 8;

    float4 xr[8], wr[4];
#pragma unroll
    for (int j = 0; j < 8; ++j) {
        const int idx = tid + 256 * j;
        const int row = idx >> 4, kq = idx & 15;
        const int r = min(rbase + row, NV - 1);
        xr[j] = *(const float4*)&X[(size_t)r * KIN + kq * 4];
    }
#pragma unroll
    for (int j = 0; j < 4; ++j) {
        const int idx = tid + 256 * j;
        const int k = idx >> 4, oq = idx & 15;
        wr[j] = *(const float4*)&Wt[(size_t)k * KOUT + oq * 4];
    }

    float acc[4][8];
#pragma unroll
    for (int i = 0; i < 4; ++i)
#pragma unroll
        for (int c = 0; c < 8; ++c) acc[i][c] = 0.0f;

    for (int ch = 0; ch < KIN / PKC; ++ch) {
        __syncthreads();
#pragma unroll
        for (int j = 0; j < 8; ++j) {
            const int idx = tid + 256 * j;
            const int row = idx >> 4, kq = idx & 15;
            *(float4*)&Xs[row * XS_LD + kq * 4] = xr[j];
        }
#pragma unroll
        for (int j = 0; j < 4; ++j) {
            const int idx = tid + 256 * j;
            const int k = idx >> 4, oq = idx & 15;
            *(float4*)&Ws[k * KOUT + oq * 4] = wr[j];
        }
        __syncthreads();

        if (ch < KIN / PKC - 1) {
            const int kc = (ch + 1) * PKC;
#pragma unroll
            for (int j = 0; j < 8; ++j) {
                const int idx = tid + 256 * j;
                const int row = idx >> 4, kq = idx & 15;
                const int r = min(rbase + row, NV - 1);
                xr[j] = *(const float4*)&X[(size_t)r * KIN + kc + kq * 4];
            }
#pragma unroll
            for (int j = 0; j < 4; ++j) {
                const int idx = tid + 256 * j;
                const int k = idx >> 4, oq = idx & 15;
                wr[j] = *(const float4*)&Wt[(size_t)(kc + k) * KOUT + oq * 4];
            }
        }

        for (int kk = 0; kk < PKC / 4; ++kk) {
            float4 xv[4], wva[4], wvb[4];
#pragma unroll
            for (int i = 0; i < 4; ++i)
                xv[i] = *(const float4*)&Xs[(rg + 32 * i) * XS_LD + kk * 4];
#pragma unroll
            for (int j = 0; j < 4; ++j) {
                wva[j] = *(const float4*)&Ws[(kk * 4 + j) * KOUT + c8];
                wvb[j] = *(const float4*)&Ws[(kk * 4 + j) * KOUT + c8 + 4];
            }
#pragma unroll
            for (int i = 0; i < 4; ++i) {
                const float x0 = xv[i].x, x1 = xv[i].y, x2 = xv[i].z, x3 = xv[i].w;
                acc[i][0] = fmaf(x0, wva[0].x, acc[i][0]);
                acc[i][1] = fmaf(x0, wva[0].y, acc[i][1]);
                acc[i][2] = fmaf(x0, wva[0].z, acc[i][2]);
                acc[i][3] = fmaf(x0, wva[0].w, acc[i][3]);
                acc[i][4] = fmaf(x0, wvb[0].x, acc[i][4]);
                acc[i][5] = fmaf(x0, wvb[0].y, acc[i][5]);
                acc[i][6] = fmaf(x0, wvb[0].z, acc[i][6]);
                acc[i][7] = fmaf(x0, wvb[0].w, acc[i][7]);
                acc[i][0] = fmaf(x1, wva[1].x, acc[i][0]);
                acc[i][1] = fmaf(x1, wva[1].y, acc[i][1]);
                acc[i][2] = fmaf(x1, wva[1].z, acc[i][2]);
                acc[i][3] = fmaf(x1, wva[1].w, acc[i][3]);
                acc[i][4] = fmaf(x1, wvb[1].x, acc[i][4]);
                acc[i][5] = fmaf(x1, wvb[1].y, acc[i][5]);
                acc[i][6] = fmaf(x1, wvb[1].z, acc[i][6]);
                acc[i][7] = fmaf(x1, wvb[1].w, acc[i][7]);
                acc[i][0] = fmaf(x2, wva[2].x, acc[i][0]);
                acc[i][1] = fmaf(x2, wva[2].y, acc[i][1]);
                acc[i][2] = fmaf(x2, wva[2].z, acc[i][2]);
                acc[i][3] = fmaf(x2, wva[2].w, acc[i][3]);
                acc[i][4] = fmaf(x2, wvb[2].x, acc[i][4]);
                acc[i][5] = fmaf(x2, wvb[2].y, acc[i][5]);
                acc[i][6] = fmaf(x2, wvb[2].z, acc[i][6]);
                acc[i][7] = fmaf(x2, wvb[2].w, acc[i][7]);
                acc[i][0] = fmaf(x3, wva[3].x, acc[i][0]);
                acc[i][1] = fmaf(x3, wva[3].y, acc[i][1]);
                acc[i][2] = fmaf(x3, wva[3].z, acc[i][2]);
                acc[i][3] = fmaf(x3, wva[3].w, acc[i][3]);
                acc[i][4] = fmaf(x3, wvb[3].x, acc[i][4]);
                acc[i][5] = fmaf(x3, wvb[3].y, acc[i][5]);
                acc[i][6] = fmaf(x3, wvb[3].z, acc[i][6]);
                acc[i][7] = fmaf(x3, wvb[3].w, acc[i][7]);
            }
        }
    }

#pragma unroll
    for (int i = 0; i < 4; ++i) {
        const int r = rbase + rg + 32 * i;
        if (r < NV) {
            uint4 pk;
            pk.x = (unsigned)f2bf(acc[i][0]) | ((unsigned)f2bf(acc[i][1]) << 16);
            pk.y = (unsigned)f2bf(acc[i][2]) | ((unsigned)f2bf(acc[i][3]) << 16);
            pk.z = (unsigned)f2bf(acc[i][4]) | ((unsigned)f2bf(acc[i][5]) << 16);
            pk.w = (unsigned)f2bf(acc[i][6]) | ((unsigned)f2bf(acc[i][7]) << 16);
            *(uint4*)&Xpb[(size_t)r * KOUT + c8] = pk;
        }
    }
}

// ---------------------------------------------------------------------------
// Per-block LDS histogram of BOTH bucket keys -> count matrix
// ---------------------------------------------------------------------------
__global__ __launch_bounds__(256) void k_hist(const int* __restrict__ v_idx,
                                              const int* __restrict__ e_idx,
                                              int* __restrict__ mat) {
    __shared__ int h[NBINS];
    const int b = blockIdx.x, tid = threadIdx.x;
    for (int i = tid; i < NBINS; i += 256) h[i] = 0;
    __syncthreads();
    const int base = b * CHUNK;
    for (int i = tid; i < CHUNK; i += 256) {
        atomicAdd(&h[e_idx[base + i] >> 6], 1);
        atomicAdd(&h[NBE + (v_idx[base + i] >> 6)], 1);
    }
    __syncthreads();
    for (int j = tid; j < NBINS; j += 256) mat[j * NB + b] = h[j];
}

// ---------------------------------------------------------------------------
// 3-kernel exclusive scan of mat[LSCAN]
// ---------------------------------------------------------------------------
__global__ __launch_bounds__(1024) void k_scan1(int* __restrict__ mat,
                                                int* __restrict__ bsum) {
    __shared__ int buf[1024];
    const int tid = threadIdx.x;
    const int i = blockIdx.x * 1024 + tid;
    const int v = (i < LSCAN) ? mat[i] : 0;
    buf[tid] = v;
    __syncthreads();
    for (int d = 1; d < 1024; d <<= 1) {
        int t = (tid >= d) ? buf[tid - d] : 0;
        __syncthreads();
        buf[tid] += t;
        __syncthreads();
    }
    if (i < LSCAN) mat[i] = buf[tid] - v;
    if (tid == 1023) bsum[blockIdx.x] = buf[1023];
}

__global__ __launch_bounds__(1024) void k_scan2(int* __restrict__ bsum) {
    __shared__ int buf[1024];
    const int tid = threadIdx.x;
    const int v = (tid < NBLK_SCAN) ? bsum[tid] : 0;
    buf[tid] = v;
    __syncthreads();
    for (int d = 1; d < 1024; d <<= 1) {
        int t = (tid >= d) ? buf[tid - d] : 0;
        __syncthreads();
        buf[tid] += t;
        __syncthreads();
    }
    if (tid < NBLK_SCAN) bsum[tid] = buf[tid] - v;
}

__global__ __launch_bounds__(1024) void k_scan3(int* __restrict__ mat,
                                                const int* __restrict__ bsum) {
    const int i = blockIdx.x * 1024 + threadIdx.x;
    if (i < LSCAN) mat[i] += bsum[blockIdx.x];
}

// ---------------------------------------------------------------------------
// Partition: LDS cursors from scanned matrix, no global atomics.
// part[p] = val | (localKey << 17)
// ---------------------------------------------------------------------------
__global__ __launch_bounds__(256) void k_partition(const int* __restrict__ key,
                                                   const int* __restrict__ val,
                                                   const int* __restrict__ mat,
                                                   int matOff, int sub, int nbkt,
                                                   unsigned* __restrict__ part) {
    extern __shared__ int cur[];
    const int b = blockIdx.x, tid = threadIdx.x;
    for (int j = tid; j < nbkt; j += 256)
        cur[j] = mat[matOff + j * NB + b] - sub;
    __syncthreads();
    const int base = b * CHUNK;
    for (int i = tid; i < CHUNK; i += 256) {
        const int k = key[base + i];
        const int p = atomicAdd(&cur[k >> 6], 1);
        part[p] = (unsigned)val[base + i] | ((unsigned)(k & 63) << 17);
    }
}

// ---------------------------------------------------------------------------
// Fused stage 1: per-bucket LDS accumulate (64 edges x 64 ch, 16 KB)
// Xe[e] = degE[e]*Wdiag[e] * sum_v Xp[v]     (bf16 table in, bf16 out)
// ---------------------------------------------------------------------------
__global__ __launch_bounds__(256) void k_edgeacc(const unsigned short* __restrict__ Xpb,
                                                 const unsigned* __restrict__ part,
                                                 const int* __restrict__ mat,
                                                 const float* __restrict__ degE,
                                                 const float* __restrict__ Wdiag,
                                                 unsigned short* __restrict__ Xeb) {
    __shared__ float accb[64 * 64];
    const int b = blockIdx.x, tid = threadIdx.x;
    const int lane = tid & 63, wv = tid >> 6;
    for (int j = tid; j < 4096; j += 256) accb[j] = 0.0f;
    const int base = mat[b * NB];
    const int end  = mat[(b + 1) * NB];   // mat[NBE*NB] == NNZ (start of V region)
    __syncthreads();

    for (int i0 = base + wv * 64; i0 < end; i0 += 256) {
        const int m = min(64, end - i0);
        const unsigned u = (i0 + lane < end) ? part[i0 + lane] : 0u;
        int t = 0;
        for (; t + 8 <= m; t += 8) {
            float xv[8]; int le[8];
#pragma unroll
            for (int z = 0; z < 8; ++z) {
                const unsigned uu = __shfl(u, t + z, 64);
                le[z] = (int)((uu >> 17) & 63u);
                xv[z] = bf2f(Xpb[(size_t)(uu & 0x1FFFFu) * KOUT + lane]);
            }
#pragma unroll
            for (int z = 0; z < 8; ++z)
                atomicAdd(&accb[le[z] * 64 + lane], xv[z]);
        }
        for (; t < m; ++t) {
            const unsigned uu = __shfl(u, t, 64);
            const float x = bf2f(Xpb[(size_t)(uu & 0x1FFFFu) * KOUT + lane]);
            atomicAdd(&accb[(int)((uu >> 17) & 63u) * 64 + lane], x);
        }
    }
    __syncthreads();

    const int e0 = b << 6;
#pragma unroll
    for (int j = 0; j < 16; ++j) {
        const int idx = tid + 256 * j;
        const int le = idx >> 6, ch = idx & 63;
        const int e = e0 + le;
        if (e < NE)
            Xeb[(size_t)e * KOUT + ch] = f2bf(accb[idx] * (degE[e] * Wdiag[e]));
    }
}

// ---------------------------------------------------------------------------
// Fused stage 2: per-bucket LDS accumulate (64 verts x 64 ch)
// out[v] = degV[v] * sum_e Xe[e]
// ---------------------------------------------------------------------------
__global__ __launch_bounds__(256) void k_vertacc(const unsigned short* __restrict__ Xeb,
                                                 const unsigned* __restrict__ part,
                                                 const int* __restrict__ mat,
                                                 const float* __restrict__ degV,
                                                 float* __restrict__ out) {
    __shared__ float accb[64 * 64];
    const int b = blockIdx.x, tid = threadIdx.x;
    const int lane = tid & 63, wv = tid >> 6;
    for (int j = tid; j < 4096; j += 256) accb[j] = 0.0f;
    const int base = mat[NBE * NB + b * NB] - NNZ;
    const int end  = (b == NBV - 1) ? NNZ : (mat[NBE * NB + (b + 1) * NB] - NNZ);
    __syncthreads();

    for (int i0 = base + wv * 64; i0 < end; i0 += 256) {
        const int m = min(64, end - i0);
        const unsigned u = (i0 + lane < end) ? part[i0 + lane] : 0u;
        int t = 0;
        for (; t + 8 <= m; t += 8) {
            float xv[8]; int lv[8];
#pragma unroll
            for (int z = 0; z < 8; ++z) {
                const unsigned uu = __shfl(u, t + z, 64);
                lv[z] = (int)((uu >> 17) & 63u);
                xv[z] = bf2f(Xeb[(size_t)(uu & 0x1FFFFu) * KOUT + lane]);
            }
#pragma unroll
            for (int z = 0; z < 8; ++z)
                atomicAdd(&accb[lv[z] * 64 + lane], xv[z]);
        }
        for (; t < m; ++t) {
            const unsigned uu = __shfl(u, t, 64);
            const float x = bf2f(Xeb[(size_t)(uu & 0x1FFFFu) * KOUT + lane]);
            atomicAdd(&accb[(int)((uu >> 17) & 63u) * 64 + lane], x);
        }
    }
    __syncthreads();

    const int v0 = b << 6;
#pragma unroll
    for (int j = 0; j < 16; ++j) {
        const int idx = tid + 256 * j;
        const int lv = idx >> 6, ch = idx & 63;
        const int v = v0 + lv;
        if (v < NV)
            out[(size_t)v * KOUT + ch] = accb[idx] * degV[v];
    }
}

extern "C" void kernel_launch(void* const* d_in, const int* in_sizes, int n_in,
                              void* d_out, int out_size, void* d_ws, size_t ws_size,
                              hipStream_t stream) {
    const float* X     = (const float*)d_in[0];
    const float* W     = (const float*)d_in[1];
    const float* degE  = (const float*)d_in[2];
    const float* degV  = (const float*)d_in[3];
    const float* Wdiag = (const float*)d_in[4];
    const int*   v_idx = (const int*)d_in[5];
    const int*   e_idx = (const int*)d_in[6];
    float* out = (float*)d_out;

    // Workspace (~36 MB). part reused for E then V phases (stream-ordered).
    unsigned short* Xpb = (unsigned short*)d_ws;          // NV*KOUT bf16 (12.8 MB)
    unsigned short* Xeb = Xpb + (size_t)NV * KOUT;        // NE*KOUT bf16 (6.4 MB)
    unsigned*       part = (unsigned*)(Xeb + (size_t)NE * KOUT);  // NNZ u32
    int*            mat  = (int*)(part + NNZ);            // LSCAN
    int*            bsum = mat + LSCAN;                   // NBLK_SCAN
    float*          Wt   = (float*)(bsum + ((NBLK_SCAN + 3) & ~3)); // KIN*KOUT

    k_wt<<<KOUT, KIN, 0, stream>>>(W, Wt);
    k_project<<<(NV + PROWS - 1) / PROWS, 256, 0, stream>>>(X, Wt, Xpb);

    k_hist<<<NB, 256, 0, stream>>>(v_idx, e_idx, mat);
    k_scan1<<<NBLK_SCAN, 1024, 0, stream>>>(mat, bsum);
    k_scan2<<<1, 1024, 0, stream>>>(bsum);
    k_scan3<<<NBLK_SCAN, 1024, 0, stream>>>(mat, bsum);

    // ---- Edge side: partition -> fused accumulate
    k_partition<<<NB, 256, NBE * sizeof(int), stream>>>(e_idx, v_idx, mat, 0, 0, NBE, part);
    k_edgeacc<<<NBE, 256, 0, stream>>>(Xpb, part, mat, degE, Wdiag, Xeb);

    // ---- Vertex side: partition -> fused accumulate (reuses part)
    k_partition<<<NB, 256, NBV * sizeof(int), stream>>>(v_idx, e_idx, mat, NBE * NB, NNZ, NBV, part);
    k_vertacc<<<NBV, 256, 0, stream>>>(Xeb, part, mat, degV, out);
}

// Round 9
// 360.256 us; speedup vs baseline: 7.8084x; 7.8084x over previous
//
#include <hip/hip_runtime.h>

#define NV   100000
#define NE   50000
#define NNZ  3200000
#define KIN  256
#define KOUT 64

#define NB    400                  // partition/hist blocks (NNZ = 400*8000 exactly)
#define CHUNK (NNZ / NB)           // 8000
#define NBE   782                  // ceil(NE/64) edge buckets
#define NBV   1563                 // ceil(NV/64) vertex buckets
#define NBINS (NBE + NBV)          // 2345
#define LSCAN (NBINS * NB)         // 938000
#define NBLK_SCAN ((LSCAN + 1023) / 1024)   // 917 (must stay <= 1024 for k_scan2)

#define PROWS 128                  // k_project tile rows
#define PKC   64                   // k_project K-chunk
#define XS_LD 68                   // Xs padded stride

__device__ __forceinline__ unsigned short f2bf(float f) {
    union { float f; unsigned u; } c{f};
    const unsigned lsb = (c.u >> 16) & 1u;
    return (unsigned short)((c.u + 0x7FFFu + lsb) >> 16);
}
__device__ __forceinline__ float bf2f_lo(unsigned u) {
    union { unsigned u; float f; } c{u << 16};
    return c.f;
}
__device__ __forceinline__ float bf2f_hi(unsigned u) {
    union { unsigned u; float f; } c{u & 0xFFFF0000u};
    return c.f;
}

// ---------------------------------------------------------------------------
// Tiny one-off: Wt[k][o] = W[o][k]
// ---------------------------------------------------------------------------
__global__ __launch_bounds__(256) void k_wt(const float* __restrict__ W,
                                            float* __restrict__ Wt) {
    const int o = blockIdx.x;
    const int k = threadIdx.x;
    Wt[k * KOUT + o] = W[o * KIN + k];
}

// ---------------------------------------------------------------------------
// Kernel 1 (round-6 structure, bf16 out): Xp[r][o] = sum_k X[r][k]*W[o][k]
// ---------------------------------------------------------------------------
__global__ __launch_bounds__(256) void k_project(const float* __restrict__ X,
                                                 const float* __restrict__ Wt,
                                                 unsigned short* __restrict__ Xpb) {
    __shared__ float Xs[PROWS * XS_LD];   // 34.8 KB
    __shared__ float Ws[PKC * KOUT];      // 16 KB

    const int tid = threadIdx.x;
    const int rbase = blockIdx.x * PROWS;
    const int rg = tid >> 3;              // rows rg, rg+32, rg+64, rg+96
    const int c8 = (tid & 7) * 8;

    float4 xr[8], wr[4];
#pragma unroll
    for (int j = 0; j < 8; ++j) {
        const int idx = tid + 256 * j;
        const int row = idx >> 4, kq = idx & 15;
        const int r = min(rbase + row, NV - 1);
        xr[j] = *(const float4*)&X[(size_t)r * KIN + kq * 4];
    }
#pragma unroll
    for (int j = 0; j < 4; ++j) {
        const int idx = tid + 256 * j;
        const int k = idx >> 4, oq = idx & 15;
        wr[j] = *(const float4*)&Wt[(size_t)k * KOUT + oq * 4];
    }

    float acc[4][8];
#pragma unroll
    for (int i = 0; i < 4; ++i)
#pragma unroll
        for (int c = 0; c < 8; ++c) acc[i][c] = 0.0f;

    for (int ch = 0; ch < KIN / PKC; ++ch) {
        __syncthreads();
#pragma unroll
        for (int j = 0; j < 8; ++j) {
            const int idx = tid + 256 * j;
            const int row = idx >> 4, kq = idx & 15;
            *(float4*)&Xs[row * XS_LD + kq * 4] = xr[j];
        }
#pragma unroll
        for (int j = 0; j < 4; ++j) {
            const int idx = tid + 256 * j;
            const int k = idx >> 4, oq = idx & 15;
            *(float4*)&Ws[k * KOUT + oq * 4] = wr[j];
        }
        __syncthreads();

        if (ch < KIN / PKC - 1) {
            const int kc = (ch + 1) * PKC;
#pragma unroll
            for (int j = 0; j < 8; ++j) {
                const int idx = tid + 256 * j;
                const int row = idx >> 4, kq = idx & 15;
                const int r = min(rbase + row, NV - 1);
                xr[j] = *(const float4*)&X[(size_t)r * KIN + kc + kq * 4];
            }
#pragma unroll
            for (int j = 0; j < 4; ++j) {
                const int idx = tid + 256 * j;
                const int k = idx >> 4, oq = idx & 15;
                wr[j] = *(const float4*)&Wt[(size_t)(kc + k) * KOUT + oq * 4];
            }
        }

        for (int kk = 0; kk < PKC / 4; ++kk) {
            float4 xv[4], wva[4], wvb[4];
#pragma unroll
            for (int i = 0; i < 4; ++i)
                xv[i] = *(const float4*)&Xs[(rg + 32 * i) * XS_LD + kk * 4];
#pragma unroll
            for (int j = 0; j < 4; ++j) {
                wva[j] = *(const float4*)&Ws[(kk * 4 + j) * KOUT + c8];
                wvb[j] = *(const float4*)&Ws[(kk * 4 + j) * KOUT + c8 + 4];
            }
#pragma unroll
            for (int i = 0; i < 4; ++i) {
                const float x0 = xv[i].x, x1 = xv[i].y, x2 = xv[i].z, x3 = xv[i].w;
                acc[i][0] = fmaf(x0, wva[0].x, acc[i][0]);
                acc[i][1] = fmaf(x0, wva[0].y, acc[i][1]);
                acc[i][2] = fmaf(x0, wva[0].z, acc[i][2]);
                acc[i][3] = fmaf(x0, wva[0].w, acc[i][3]);
                acc[i][4] = fmaf(x0, wvb[0].x, acc[i][4]);
                acc[i][5] = fmaf(x0, wvb[0].y, acc[i][5]);
                acc[i][6] = fmaf(x0, wvb[0].z, acc[i][6]);
                acc[i][7] = fmaf(x0, wvb[0].w, acc[i][7]);
                acc[i][0] = fmaf(x1, wva[1].x, acc[i][0]);
                acc[i][1] = fmaf(x1, wva[1].y, acc[i][1]);
                acc[i][2] = fmaf(x1, wva[1].z, acc[i][2]);
                acc[i][3] = fmaf(x1, wva[1].w, acc[i][3]);
                acc[i][4] = fmaf(x1, wvb[1].x, acc[i][4]);
                acc[i][5] = fmaf(x1, wvb[1].y, acc[i][5]);
                acc[i][6] = fmaf(x1, wvb[1].z, acc[i][6]);
                acc[i][7] = fmaf(x1, wvb[1].w, acc[i][7]);
                acc[i][0] = fmaf(x2, wva[2].x, acc[i][0]);
                acc[i][1] = fmaf(x2, wva[2].y, acc[i][1]);
                acc[i][2] = fmaf(x2, wva[2].z, acc[i][2]);
                acc[i][3] = fmaf(x2, wva[2].w, acc[i][3]);
                acc[i][4] = fmaf(x2, wvb[2].x, acc[i][4]);
                acc[i][5] = fmaf(x2, wvb[2].y, acc[i][5]);
                acc[i][6] = fmaf(x2, wvb[2].z, acc[i][6]);
                acc[i][7] = fmaf(x2, wvb[2].w, acc[i][7]);
                acc[i][0] = fmaf(x3, wva[3].x, acc[i][0]);
                acc[i][1] = fmaf(x3, wva[3].y, acc[i][1]);
                acc[i][2] = fmaf(x3, wva[3].z, acc[i][2]);
                acc[i][3] = fmaf(x3, wva[3].w, acc[i][3]);
                acc[i][4] = fmaf(x3, wvb[3].x, acc[i][4]);
                acc[i][5] = fmaf(x3, wvb[3].y, acc[i][5]);
                acc[i][6] = fmaf(x3, wvb[3].z, acc[i][6]);
                acc[i][7] = fmaf(x3, wvb[3].w, acc[i][7]);
            }
        }
    }

#pragma unroll
    for (int i = 0; i < 4; ++i) {
        const int r = rbase + rg + 32 * i;
        if (r < NV) {
            uint4 pk;
            pk.x = (unsigned)f2bf(acc[i][0]) | ((unsigned)f2bf(acc[i][1]) << 16);
            pk.y = (unsigned)f2bf(acc[i][2]) | ((unsigned)f2bf(acc[i][3]) << 16);
            pk.z = (unsigned)f2bf(acc[i][4]) | ((unsigned)f2bf(acc[i][5]) << 16);
            pk.w = (unsigned)f2bf(acc[i][6]) | ((unsigned)f2bf(acc[i][7]) << 16);
            *(uint4*)&Xpb[(size_t)r * KOUT + c8] = pk;
        }
    }
}

// ---------------------------------------------------------------------------
// Per-block LDS histogram of BOTH bucket keys -> count matrix
// ---------------------------------------------------------------------------
__global__ __launch_bounds__(256) void k_hist(const int* __restrict__ v_idx,
                                              const int* __restrict__ e_idx,
                                              int* __restrict__ mat) {
    __shared__ int h[NBINS];
    const int b = blockIdx.x, tid = threadIdx.x;
    for (int i = tid; i < NBINS; i += 256) h[i] = 0;
    __syncthreads();
    const int base = b * CHUNK;
    for (int i = tid; i < CHUNK; i += 256) {
        atomicAdd(&h[e_idx[base + i] >> 6], 1);
        atomicAdd(&h[NBE + (v_idx[base + i] >> 6)], 1);
    }
    __syncthreads();
    for (int j = tid; j < NBINS; j += 256) mat[j * NB + b] = h[j];
}

// ---------------------------------------------------------------------------
// 3-kernel exclusive scan of mat[LSCAN]
// ---------------------------------------------------------------------------
__global__ __launch_bounds__(1024) void k_scan1(int* __restrict__ mat,
                                                int* __restrict__ bsum) {
    __shared__ int buf[1024];
    const int tid = threadIdx.x;
    const int i = blockIdx.x * 1024 + tid;
    const int v = (i < LSCAN) ? mat[i] : 0;
    buf[tid] = v;
    __syncthreads();
    for (int d = 1; d < 1024; d <<= 1) {
        int t = (tid >= d) ? buf[tid - d] : 0;
        __syncthreads();
        buf[tid] += t;
        __syncthreads();
    }
    if (i < LSCAN) mat[i] = buf[tid] - v;
    if (tid == 1023) bsum[blockIdx.x] = buf[1023];
}

__global__ __launch_bounds__(1024) void k_scan2(int* __restrict__ bsum) {
    __shared__ int buf[1024];
    const int tid = threadIdx.x;
    const int v = (tid < NBLK_SCAN) ? bsum[tid] : 0;
    buf[tid] = v;
    __syncthreads();
    for (int d = 1; d < 1024; d <<= 1) {
        int t = (tid >= d) ? buf[tid - d] : 0;
        __syncthreads();
        buf[tid] += t;
        __syncthreads();
    }
    if (tid < NBLK_SCAN) bsum[tid] = buf[tid] - v;
}

__global__ __launch_bounds__(1024) void k_scan3(int* __restrict__ mat,
                                                const int* __restrict__ bsum) {
    const int i = blockIdx.x * 1024 + threadIdx.x;
    if (i < LSCAN) mat[i] += bsum[blockIdx.x];
}

// ---------------------------------------------------------------------------
// Partition: LDS cursors from scanned matrix, no global atomics.
// part[p] = val | (localKey << 17)
// ---------------------------------------------------------------------------
__global__ __launch_bounds__(256) void k_partition(const int* __restrict__ key,
                                                   const int* __restrict__ val,
                                                   const int* __restrict__ mat,
                                                   int matOff, int sub, int nbkt,
                                                   unsigned* __restrict__ part) {
    extern __shared__ int cur[];
    const int b = blockIdx.x, tid = threadIdx.x;
    for (int j = tid; j < nbkt; j += 256)
        cur[j] = mat[matOff + j * NB + b] - sub;
    __syncthreads();
    const int base = b * CHUNK;
    for (int i = tid; i < CHUNK; i += 256) {
        const int k = key[base + i];
        const int p = atomicAdd(&cur[k >> 6], 1);
        part[p] = (unsigned)val[base + i] | ((unsigned)(k & 63) << 17);
    }
}

// ---------------------------------------------------------------------------
// Per-bucket counting sort -> CSR offsets + ordered adj
// ---------------------------------------------------------------------------
__global__ __launch_bounds__(256) void k_buildcsr(const unsigned* __restrict__ part,
                                                  const int* __restrict__ mat,
                                                  int matOff, int sub,
                                                  int* __restrict__ offOut,
                                                  int* __restrict__ adj,
                                                  int nMajor) {
    const int b = blockIdx.x;
    const int tid = threadIdx.x;
    const int base = mat[matOff + b * NB] - sub;
    const int end  = (b == (int)gridDim.x - 1) ? NNZ : (mat[matOff + (b + 1) * NB] - sub);
    const int nb = end - base;
    const int k0 = b << 6;

    __shared__ int hist[64], cur[64];
    if (tid < 64) hist[tid] = 0;
    __syncthreads();

    for (int i = tid; i < nb; i += 256)
        atomicAdd(&hist[(part[base + i] >> 17) & 63], 1);
    __syncthreads();

    if (tid == 0) {
        int s = 0;
        for (int k = 0; k < 64; ++k) {
            int h = hist[k];
            hist[k] = s;
            cur[k] = s;
            s += h;
        }
    }
    __syncthreads();

    const int lim = min(64, nMajor - k0);
    if (tid < lim) offOut[k0 + tid] = base + hist[tid];
    if (b == 0 && tid == 0) offOut[nMajor] = NNZ;

    for (int i = tid; i < nb; i += 256) {
        const unsigned u = part[base + i];
        const int lk = (u >> 17) & 63;
        adj[base + atomicAdd(&cur[lk], 1)] = (int)(u & 0x1FFFFu);
    }
}

// ---------------------------------------------------------------------------
// Stage 1 (pull, half-wave-paired): one wave per edge.
// lane -> channel pair (2 bf16 via u32); half h processes entries 2t+h.
// Combine halves with one shfl_xor(32) at the end.
// ---------------------------------------------------------------------------
__global__ __launch_bounds__(256) void k_gatherE(const unsigned short* __restrict__ Xpb,
                                                 const int* __restrict__ offE,
                                                 const int* __restrict__ adj,
                                                 const float* __restrict__ degE,
                                                 const float* __restrict__ Wdiag,
                                                 unsigned short* __restrict__ Xeb) {
    const int wave = (blockIdx.x * 256 + threadIdx.x) >> 6;
    const int lane = threadIdx.x & 63;
    const int sl   = lane & 31;
    const int half = lane >> 5;
    if (wave >= NE) return;
    const int b = offE[wave];
    const int e = offE[wave + 1];
    float ax = 0.0f, ay = 0.0f;
    for (int base = b; base < e; base += 64) {
        const int m = min(64, e - base);
        const int vi = (base + lane < e) ? adj[base + lane] : 0;
        const int tmf = m >> 1;            // full pair iterations
        int t = 0;
        for (; t + 8 <= tmf; t += 8) {
            unsigned u[8];
#pragma unroll
            for (int z = 0; z < 8; ++z) {
                const int idx = __shfl(vi, 2 * (t + z) + half, 64);
                u[z] = *(const unsigned*)&Xpb[(size_t)idx * KOUT + 2 * sl];
            }
#pragma unroll
            for (int z = 0; z < 8; ++z) {
                ax += bf2f_lo(u[z]);
                ay += bf2f_hi(u[z]);
            }
        }
        const int tm = (m + 1) >> 1;       // tail (uniform bound, predicated)
        for (; t < tm; ++t) {
            const int src = 2 * t + half;
            const int idx = __shfl(vi, src, 64);
            const unsigned u = *(const unsigned*)&Xpb[(size_t)idx * KOUT + 2 * sl];
            if (src < m) { ax += bf2f_lo(u); ay += bf2f_hi(u); }
        }
    }
    ax += __shfl_xor(ax, 32, 64);
    ay += __shfl_xor(ay, 32, 64);
    if (half == 0) {
        const float s = degE[wave] * Wdiag[wave];
        const unsigned pk = (unsigned)f2bf(ax * s) | ((unsigned)f2bf(ay * s) << 16);
        *(unsigned*)&Xeb[(size_t)wave * KOUT + 2 * sl] = pk;
    }
}

// ---------------------------------------------------------------------------
// Stage 2 (pull, half-wave-paired): one wave per vertex; fp32 out.
// ---------------------------------------------------------------------------
__global__ __launch_bounds__(256) void k_gatherV(const unsigned short* __restrict__ Xeb,
                                                 const int* __restrict__ offV,
                                                 const int* __restrict__ adj,
                                                 const float* __restrict__ degV,
                                                 float* __restrict__ out) {
    const int wave = (blockIdx.x * 256 + threadIdx.x) >> 6;
    const int lane = threadIdx.x & 63;
    const int sl   = lane & 31;
    const int half = lane >> 5;
    if (wave >= NV) return;
    const int b = offV[wave];
    const int e = offV[wave + 1];
    float ax = 0.0f, ay = 0.0f;
    for (int base = b; base < e; base += 64) {
        const int m = min(64, e - base);
        const int ei = (base + lane < e) ? adj[base + lane] : 0;
        const int tmf = m >> 1;
        int t = 0;
        for (; t + 8 <= tmf; t += 8) {
            unsigned u[8];
#pragma unroll
            for (int z = 0; z < 8; ++z) {
                const int idx = __shfl(ei, 2 * (t + z) + half, 64);
                u[z] = *(const unsigned*)&Xeb[(size_t)idx * KOUT + 2 * sl];
            }
#pragma unroll
            for (int z = 0; z < 8; ++z) {
                ax += bf2f_lo(u[z]);
                ay += bf2f_hi(u[z]);
            }
        }
        const int tm = (m + 1) >> 1;
        for (; t < tm; ++t) {
            const int src = 2 * t + half;
            const int idx = __shfl(ei, src, 64);
            const unsigned u = *(const unsigned*)&Xeb[(size_t)idx * KOUT + 2 * sl];
            if (src < m) { ax += bf2f_lo(u); ay += bf2f_hi(u); }
        }
    }
    ax += __shfl_xor(ax, 32, 64);
    ay += __shfl_xor(ay, 32, 64);
    if (half == 0) {
        const float s = degV[wave];
        *(float2*)&out[(size_t)wave * KOUT + 2 * sl] = make_float2(ax * s, ay * s);
    }
}

extern "C" void kernel_launch(void* const* d_in, const int* in_sizes, int n_in,
                              void* d_out, int out_size, void* d_ws, size_t ws_size,
                              hipStream_t stream) {
    const float* X     = (const float*)d_in[0];
    const float* W     = (const float*)d_in[1];
    const float* degE  = (const float*)d_in[2];
    const float* degV  = (const float*)d_in[3];
    const float* Wdiag = (const float*)d_in[4];
    const int*   v_idx = (const int*)d_in[5];
    const int*   e_idx = (const int*)d_in[6];
    float* out = (float*)d_out;

    // Workspace (~50 MB). part/adj reused for E then V phases (stream-ordered).
    unsigned short* Xpb = (unsigned short*)d_ws;            // NV*KOUT bf16 (12.8 MB)
    unsigned short* Xeb = Xpb + (size_t)NV * KOUT;          // NE*KOUT bf16 (6.4 MB)
    int*      adj  = (int*)(Xeb + (size_t)NE * KOUT);       // NNZ
    unsigned* part = (unsigned*)(adj + NNZ);                // NNZ
    int*      offE = (int*)(part + NNZ);                    // NE+1
    int*      offV = offE + (NE + 1);                       // NV+1
    int*      mat  = offV + (NV + 1);                       // LSCAN
    int*      bsum = mat + LSCAN;                           // NBLK_SCAN
    float*    Wt   = (float*)(bsum + ((NBLK_SCAN + 3) & ~3)); // KIN*KOUT

    k_wt<<<KOUT, KIN, 0, stream>>>(W, Wt);
    k_project<<<(NV + PROWS - 1) / PROWS, 256, 0, stream>>>(X, Wt, Xpb);

    k_hist<<<NB, 256, 0, stream>>>(v_idx, e_idx, mat);
    k_scan1<<<NBLK_SCAN, 1024, 0, stream>>>(mat, bsum);
    k_scan2<<<1, 1024, 0, stream>>>(bsum);
    k_scan3<<<NBLK_SCAN, 1024, 0, stream>>>(mat, bsum);

    // ---- Edge side: partition -> CSR -> gather
    k_partition<<<NB, 256, NBE * sizeof(int), stream>>>(e_idx, v_idx, mat, 0, 0, NBE, part);
    k_buildcsr<<<NBE, 256, 0, stream>>>(part, mat, 0, 0, offE, adj, NE);
    k_gatherE<<<(NE * 64) / 256, 256, 0, stream>>>(Xpb, offE, adj, degE, Wdiag, Xeb);

    // ---- Vertex side: partition -> CSR -> gather (reuses part/adj)
    k_partition<<<NB, 256, NBV * sizeof(int), stream>>>(v_idx, e_idx, mat, NBE * NB, NNZ, NBV, part);
    k_buildcsr<<<NBV, 256, 0, stream>>>(part, mat, NBE * NB, NNZ, offV, adj, NV);
    k_gatherV<<<(NV * 64) / 256, 256, 0, stream>>>(Xeb, offV, adj, degV, out);
}

// Round 10
// 297.895 us; speedup vs baseline: 9.4430x; 1.2093x over previous
//
#include <hip/hip_runtime.h>

#define NV   100000
#define NE   50000
#define NNZ  3200000
#define KIN  256
#define KOUT 64

#define NB    400                  // partition/hist blocks (NNZ = 400*8000 exactly)
#define CHUNK (NNZ / NB)           // 8000
#define NBE   782                  // ceil(NE/64) edge buckets
#define NBV   1563                 // ceil(NV/64) vertex buckets
#define NBINS (NBE + NBV)          // 2345
#define LSCAN (NBINS * NB)         // 938000
#define NBLK_SCAN ((LSCAN + 1023) / 1024)   // 917 (must stay <= 1024 for k_scan2)

typedef short short8 __attribute__((ext_vector_type(8)));
typedef float f32x4  __attribute__((ext_vector_type(4)));

__device__ __forceinline__ unsigned short f2bf(float f) {
    union { float f; unsigned u; } c{f};
    const unsigned lsb = (c.u >> 16) & 1u;
    return (unsigned short)((c.u + 0x7FFFu + lsb) >> 16);
}
__device__ __forceinline__ float bf2f_lo(unsigned u) {
    union { unsigned u; float f; } c{u << 16};
    return c.f;
}
__device__ __forceinline__ float bf2f_hi(unsigned u) {
    union { unsigned u; float f; } c{u & 0xFFFF0000u};
    return c.f;
}
__device__ __forceinline__ short8 pack8(const float4 lo, const float4 hi) {
    short8 r;
    r[0] = (short)f2bf(lo.x); r[1] = (short)f2bf(lo.y);
    r[2] = (short)f2bf(lo.z); r[3] = (short)f2bf(lo.w);
    r[4] = (short)f2bf(hi.x); r[5] = (short)f2bf(hi.y);
    r[6] = (short)f2bf(hi.z); r[7] = (short)f2bf(hi.w);
    return r;
}

// ---------------------------------------------------------------------------
// One-off: Wb[o][k] = bf16(W[o][k])   (32 KB, L1-resident for the GEMM)
// ---------------------------------------------------------------------------
__global__ __launch_bounds__(256) void k_wb(const float* __restrict__ W,
                                            unsigned short* __restrict__ Wb) {
    const int i = blockIdx.x * 256 + threadIdx.x;   // 16384 values
    Wb[i] = f2bf(W[i]);
}

// ---------------------------------------------------------------------------
// Kernel 1: Xp[r][o] = sum_k X[r][k]*W[o][k] — zero-LDS bf16 MFMA.
// mfma_f32_16x16x32_bf16 fragments (m89-verified C/D layout):
//   A (lane l): X[rbase + (l&15)][k0 + (l>>4)*8 + j]  -> 8 contig f32, cvt
//   B (lane l): Wb[g*16 + (l&15)][k0 + (l>>4)*8 + j]  -> 8 contig bf16
//   D (lane l, reg i): row (l>>4)*4+i, col l&15
// Per wave: 32 rows (2 A-tiles) x 64 ch (4 B-groups); 8 k-steps of 32.
// ---------------------------------------------------------------------------
__global__ __launch_bounds__(256) void k_project(const float* __restrict__ X,
                                                 const unsigned short* __restrict__ Wb,
                                                 unsigned short* __restrict__ Xpb) {
    const int tid  = threadIdx.x;
    const int lane = tid & 63;
    const int wv   = tid >> 6;
    const int l15  = lane & 15;
    const int l4   = lane >> 4;                  // 0..3
    const int rbase = blockIdx.x * 128 + wv * 32;

    const int r0 = min(rbase + l15,      NV - 1);   // clamp loads; stores guarded
    const int r1 = min(rbase + 16 + l15, NV - 1);
    const float* xp0 = X + (size_t)r0 * KIN + l4 * 8;
    const float* xp1 = X + (size_t)r1 * KIN + l4 * 8;
    const unsigned short* wp = Wb + (size_t)l15 * KIN + l4 * 8;

    f32x4 acc[2][4];
#pragma unroll
    for (int t = 0; t < 2; ++t)
#pragma unroll
        for (int g = 0; g < 4; ++g)
            acc[t][g] = (f32x4){0.f, 0.f, 0.f, 0.f};

#pragma unroll
    for (int s = 0; s < 8; ++s) {
        const int k0 = s * 32;
        const float4 a0lo = *(const float4*)(xp0 + k0);
        const float4 a0hi = *(const float4*)(xp0 + k0 + 4);
        const float4 a1lo = *(const float4*)(xp1 + k0);
        const float4 a1hi = *(const float4*)(xp1 + k0 + 4);
        short8 b[4];
#pragma unroll
        for (int g = 0; g < 4; ++g)
            b[g] = *(const short8*)(wp + (size_t)g * 16 * KIN + k0);
        const short8 a0 = pack8(a0lo, a0hi);
        const short8 a1 = pack8(a1lo, a1hi);
#pragma unroll
        for (int g = 0; g < 4; ++g) {
            acc[0][g] = __builtin_amdgcn_mfma_f32_16x16x32_bf16(a0, b[g], acc[0][g], 0, 0, 0);
            acc[1][g] = __builtin_amdgcn_mfma_f32_16x16x32_bf16(a1, b[g], acc[1][g], 0, 0, 0);
        }
    }

#pragma unroll
    for (int t = 0; t < 2; ++t)
#pragma unroll
        for (int i = 0; i < 4; ++i) {
            const int r = rbase + t * 16 + l4 * 4 + i;
            if (r < NV) {
#pragma unroll
                for (int g = 0; g < 4; ++g)
                    Xpb[(size_t)r * KOUT + g * 16 + l15] = f2bf(acc[t][g][i]);
            }
        }
}

// ---------------------------------------------------------------------------
// Per-block LDS histogram of BOTH bucket keys -> count matrix
// ---------------------------------------------------------------------------
__global__ __launch_bounds__(256) void k_hist(const int* __restrict__ v_idx,
                                              const int* __restrict__ e_idx,
                                              int* __restrict__ mat) {
    __shared__ int h[NBINS];
    const int b = blockIdx.x, tid = threadIdx.x;
    for (int i = tid; i < NBINS; i += 256) h[i] = 0;
    __syncthreads();
    const int base = b * CHUNK;
    for (int i = tid; i < CHUNK; i += 256) {
        atomicAdd(&h[e_idx[base + i] >> 6], 1);
        atomicAdd(&h[NBE + (v_idx[base + i] >> 6)], 1);
    }
    __syncthreads();
    for (int j = tid; j < NBINS; j += 256) mat[j * NB + b] = h[j];
}

// ---------------------------------------------------------------------------
// 3-kernel exclusive scan of mat[LSCAN]
// ---------------------------------------------------------------------------
__global__ __launch_bounds__(1024) void k_scan1(int* __restrict__ mat,
                                                int* __restrict__ bsum) {
    __shared__ int buf[1024];
    const int tid = threadIdx.x;
    const int i = blockIdx.x * 1024 + tid;
    const int v = (i < LSCAN) ? mat[i] : 0;
    buf[tid] = v;
    __syncthreads();
    for (int d = 1; d < 1024; d <<= 1) {
        int t = (tid >= d) ? buf[tid - d] : 0;
        __syncthreads();
        buf[tid] += t;
        __syncthreads();
    }
    if (i < LSCAN) mat[i] = buf[tid] - v;
    if (tid == 1023) bsum[blockIdx.x] = buf[1023];
}

__global__ __launch_bounds__(1024) void k_scan2(int* __restrict__ bsum) {
    __shared__ int buf[1024];
    const int tid = threadIdx.x;
    const int v = (tid < NBLK_SCAN) ? bsum[tid] : 0;
    buf[tid] = v;
    __syncthreads();
    for (int d = 1; d < 1024; d <<= 1) {
        int t = (tid >= d) ? buf[tid - d] : 0;
        __syncthreads();
        buf[tid] += t;
        __syncthreads();
    }
    if (tid < NBLK_SCAN) bsum[tid] = buf[tid] - v;
}

__global__ __launch_bounds__(1024) void k_scan3(int* __restrict__ mat,
                                                const int* __restrict__ bsum) {
    const int i = blockIdx.x * 1024 + threadIdx.x;
    if (i < LSCAN) mat[i] += bsum[blockIdx.x];
}

// ---------------------------------------------------------------------------
// Partition: LDS cursors from scanned matrix, no global atomics.
// part[p] = val | (localKey << 17)
// ---------------------------------------------------------------------------
__global__ __launch_bounds__(256) void k_partition(const int* __restrict__ key,
                                                   const int* __restrict__ val,
                                                   const int* __restrict__ mat,
                                                   int matOff, int sub, int nbkt,
                                                   unsigned* __restrict__ part) {
    extern __shared__ int cur[];
    const int b = blockIdx.x, tid = threadIdx.x;
    for (int j = tid; j < nbkt; j += 256)
        cur[j] = mat[matOff + j * NB + b] - sub;
    __syncthreads();
    const int base = b * CHUNK;
    for (int i = tid; i < CHUNK; i += 256) {
        const int k = key[base + i];
        const int p = atomicAdd(&cur[k >> 6], 1);
        part[p] = (unsigned)val[base + i] | ((unsigned)(k & 63) << 17);
    }
}

// ---------------------------------------------------------------------------
// Per-bucket counting sort -> CSR offsets + ordered adj (T = int or u16)
// ---------------------------------------------------------------------------
template <typename T>
__global__ __launch_bounds__(256) void k_buildcsr(const unsigned* __restrict__ part,
                                                  const int* __restrict__ mat,
                                                  int matOff, int sub,
                                                  int* __restrict__ offOut,
                                                  T* __restrict__ adj,
                                                  int nMajor) {
    const int b = blockIdx.x;
    const int tid = threadIdx.x;
    const int base = mat[matOff + b * NB] - sub;
    const int end  = (b == (int)gridDim.x - 1) ? NNZ : (mat[matOff + (b + 1) * NB] - sub);
    const int nb = end - base;
    const int k0 = b << 6;

    __shared__ int hist[64], cur[64];
    if (tid < 64) hist[tid] = 0;
    __syncthreads();

    for (int i = tid; i < nb; i += 256)
        atomicAdd(&hist[(part[base + i] >> 17) & 63], 1);
    __syncthreads();

    if (tid == 0) {
        int s = 0;
        for (int k = 0; k < 64; ++k) {
            int h = hist[k];
            hist[k] = s;
            cur[k] = s;
            s += h;
        }
    }
    __syncthreads();

    const int lim = min(64, nMajor - k0);
    if (tid < lim) offOut[k0 + tid] = base + hist[tid];
    if (b == 0 && tid == 0) offOut[nMajor] = NNZ;

    for (int i = tid; i < nb; i += 256) {
        const unsigned u = part[base + i];
        const int lk = (u >> 17) & 63;
        adj[base + atomicAdd(&cur[lk], 1)] = (T)(u & 0x1FFFFu);
    }
}

// ---------------------------------------------------------------------------
// Stage 1 (pull, half-wave-paired): one wave per edge.
// ---------------------------------------------------------------------------
__global__ __launch_bounds__(256) void k_gatherE(const unsigned short* __restrict__ Xpb,
                                                 const int* __restrict__ offE,
                                                 const int* __restrict__ adj,
                                                 const float* __restrict__ degE,
                                                 const float* __restrict__ Wdiag,
                                                 unsigned short* __restrict__ Xeb) {
    const int wave = (blockIdx.x * 256 + threadIdx.x) >> 6;
    const int lane = threadIdx.x & 63;
    const int sl   = lane & 31;
    const int half = lane >> 5;
    if (wave >= NE) return;
    const int b = offE[wave];
    const int e = offE[wave + 1];
    float ax = 0.0f, ay = 0.0f;
    for (int base = b; base < e; base += 64) {
        const int m = min(64, e - base);
        const int vi = (base + lane < e) ? adj[base + lane] : 0;
        const int tmf = m >> 1;
        int t = 0;
        for (; t + 8 <= tmf; t += 8) {
            unsigned u[8];
#pragma unroll
            for (int z = 0; z < 8; ++z) {
                const int idx = __shfl(vi, 2 * (t + z) + half, 64);
                u[z] = *(const unsigned*)&Xpb[(size_t)idx * KOUT + 2 * sl];
            }
#pragma unroll
            for (int z = 0; z < 8; ++z) {
                ax += bf2f_lo(u[z]);
                ay += bf2f_hi(u[z]);
            }
        }
        const int tm = (m + 1) >> 1;
        for (; t < tm; ++t) {
            const int src = 2 * t + half;
            const int idx = __shfl(vi, src, 64);
            const unsigned u = *(const unsigned*)&Xpb[(size_t)idx * KOUT + 2 * sl];
            if (src < m) { ax += bf2f_lo(u); ay += bf2f_hi(u); }
        }
    }
    ax += __shfl_xor(ax, 32, 64);
    ay += __shfl_xor(ay, 32, 64);
    if (half == 0) {
        const float s = degE[wave] * Wdiag[wave];
        const unsigned pk = (unsigned)f2bf(ax * s) | ((unsigned)f2bf(ay * s) << 16);
        *(unsigned*)&Xeb[(size_t)wave * KOUT + 2 * sl] = pk;
    }
}

// ---------------------------------------------------------------------------
// Stage 2 (pull, half-wave-paired): one wave per vertex; u16 adjacency.
// ---------------------------------------------------------------------------
__global__ __launch_bounds__(256) void k_gatherV(const unsigned short* __restrict__ Xeb,
                                                 const int* __restrict__ offV,
                                                 const unsigned short* __restrict__ adj,
                                                 const float* __restrict__ degV,
                                                 float* __restrict__ out) {
    const int wave = (blockIdx.x * 256 + threadIdx.x) >> 6;
    const int lane = threadIdx.x & 63;
    const int sl   = lane & 31;
    const int half = lane >> 5;
    if (wave >= NV) return;
    const int b = offV[wave];
    const int e = offV[wave + 1];
    float ax = 0.0f, ay = 0.0f;
    for (int base = b; base < e; base += 64) {
        const int m = min(64, e - base);
        const int ei = (base + lane < e) ? (int)adj[base + lane] : 0;
        const int tmf = m >> 1;
        int t = 0;
        for (; t + 8 <= tmf; t += 8) {
            unsigned u[8];
#pragma unroll
            for (int z = 0; z < 8; ++z) {
                const int idx = __shfl(ei, 2 * (t + z) + half, 64);
                u[z] = *(const unsigned*)&Xeb[(size_t)idx * KOUT + 2 * sl];
            }
#pragma unroll
            for (int z = 0; z < 8; ++z) {
                ax += bf2f_lo(u[z]);
                ay += bf2f_hi(u[z]);
            }
        }
        const int tm = (m + 1) >> 1;
        for (; t < tm; ++t) {
            const int src = 2 * t + half;
            const int idx = __shfl(ei, src, 64);
            const unsigned u = *(const unsigned*)&Xeb[(size_t)idx * KOUT + 2 * sl];
            if (src < m) { ax += bf2f_lo(u); ay += bf2f_hi(u); }
        }
    }
    ax += __shfl_xor(ax, 32, 64);
    ay += __shfl_xor(ay, 32, 64);
    if (half == 0) {
        const float s = degV[wave];
        *(float2*)&out[(size_t)wave * KOUT + 2 * sl] = make_float2(ax * s, ay * s);
    }
}

extern "C" void kernel_launch(void* const* d_in, const int* in_sizes, int n_in,
                              void* d_out, int out_size, void* d_ws, size_t ws_size,
                              hipStream_t stream) {
    const float* X     = (const float*)d_in[0];
    const float* W     = (const float*)d_in[1];
    const float* degE  = (const float*)d_in[2];
    const float* degV  = (const float*)d_in[3];
    const float* Wdiag = (const float*)d_in[4];
    const int*   v_idx = (const int*)d_in[5];
    const int*   e_idx = (const int*)d_in[6];
    float* out = (float*)d_out;

    // Workspace (~50 MB). part/adj reused for E then V phases (stream-ordered).
    unsigned short* Xpb = (unsigned short*)d_ws;            // NV*KOUT bf16 (12.8 MB)
    unsigned short* Xeb = Xpb + (size_t)NV * KOUT;          // NE*KOUT bf16 (6.4 MB)
    int*      adj  = (int*)(Xeb + (size_t)NE * KOUT);       // NNZ (E: int, V: u16 view)
    unsigned* part = (unsigned*)(adj + NNZ);                // NNZ
    int*      offE = (int*)(part + NNZ);                    // NE+1
    int*      offV = offE + (NE + 1);                       // NV+1
    int*      mat  = offV + (NV + 1);                       // LSCAN
    int*      bsum = mat + LSCAN;                           // NBLK_SCAN
    unsigned short* Wb = (unsigned short*)(bsum + ((NBLK_SCAN + 3) & ~3)); // 32 KB

    k_wb<<<(KIN * KOUT) / 256, 256, 0, stream>>>(W, Wb);
    k_project<<<(NV + 127) / 128, 256, 0, stream>>>(X, Wb, Xpb);

    k_hist<<<NB, 256, 0, stream>>>(v_idx, e_idx, mat);
    k_scan1<<<NBLK_SCAN, 1024, 0, stream>>>(mat, bsum);
    k_scan2<<<1, 1024, 0, stream>>>(bsum);
    k_scan3<<<NBLK_SCAN, 1024, 0, stream>>>(mat, bsum);

    // ---- Edge side: partition -> CSR(int adj) -> gather
    k_partition<<<NB, 256, NBE * sizeof(int), stream>>>(e_idx, v_idx, mat, 0, 0, NBE, part);
    k_buildcsr<int><<<NBE, 256, 0, stream>>>(part, mat, 0, 0, offE, adj, NE);
    k_gatherE<<<(NE * 64) / 256, 256, 0, stream>>>(Xpb, offE, adj, degE, Wdiag, Xeb);

    // ---- Vertex side: partition -> CSR(u16 adj) -> gather (reuses part/adj)
    k_partition<<<NB, 256, NBV * sizeof(int), stream>>>(v_idx, e_idx, mat, NBE * NB, NNZ, NBV, part);
    k_buildcsr<unsigned short><<<NBV, 256, 0, stream>>>(part, mat, NBE * NB, NNZ, offV,
                                                        (unsigned short*)adj, NV);
    k_gatherV<<<(NV * 64) / 256, 256, 0, stream>>>(Xeb, offV, (unsigned short*)adj, degV, out);
}

// Round 11
// 289.308 us; speedup vs baseline: 9.7232x; 1.0297x over previous
//
#include <hip/hip_runtime.h>

#define NV   100000
#define NE   50000
#define NNZ  3200000
#define KIN  256
#define KOUT 64

#define NB    400                  // partition/hist blocks (NNZ = 400*8000 exactly)
#define CHUNK (NNZ / NB)           // 8000
#define NBE   782                  // ceil(NE/64) edge buckets
#define NBV   1563                 // ceil(NV/64) vertex buckets
#define NBINS (NBE + NBV)          // 2345
#define LSCAN (NBINS * NB)         // 938000
#define NBLK_SCAN ((LSCAN + 1023) / 1024)   // 917 (must stay <= 1024 for k_scan2)

typedef short short8 __attribute__((ext_vector_type(8)));
typedef float f32x4  __attribute__((ext_vector_type(4)));

__device__ __forceinline__ unsigned short f2bf(float f) {
    union { float f; unsigned u; } c{f};
    const unsigned lsb = (c.u >> 16) & 1u;
    return (unsigned short)((c.u + 0x7FFFu + lsb) >> 16);
}
__device__ __forceinline__ float bf2f_lo(unsigned u) {
    union { unsigned u; float f; } c{u << 16};
    return c.f;
}
__device__ __forceinline__ float bf2f_hi(unsigned u) {
    union { unsigned u; float f; } c{u & 0xFFFF0000u};
    return c.f;
}
__device__ __forceinline__ short8 pack8(const float4 lo, const float4 hi) {
    short8 r;
    r[0] = (short)f2bf(lo.x); r[1] = (short)f2bf(lo.y);
    r[2] = (short)f2bf(lo.z); r[3] = (short)f2bf(lo.w);
    r[4] = (short)f2bf(hi.x); r[5] = (short)f2bf(hi.y);
    r[6] = (short)f2bf(hi.z); r[7] = (short)f2bf(hi.w);
    return r;
}

// ---------------------------------------------------------------------------
// One-off: Wb[o][k] = bf16(W[o][k])
// ---------------------------------------------------------------------------
__global__ __launch_bounds__(256) void k_wb(const float* __restrict__ W,
                                            unsigned short* __restrict__ Wb) {
    const int i = blockIdx.x * 256 + threadIdx.x;
    Wb[i] = f2bf(W[i]);
}

// ---------------------------------------------------------------------------
// Kernel 1: zero-LDS bf16 MFMA GEMM (round-10, verified absmax 1.0)
// ---------------------------------------------------------------------------
__global__ __launch_bounds__(256) void k_project(const float* __restrict__ X,
                                                 const unsigned short* __restrict__ Wb,
                                                 unsigned short* __restrict__ Xpb) {
    const int tid  = threadIdx.x;
    const int lane = tid & 63;
    const int wv   = tid >> 6;
    const int l15  = lane & 15;
    const int l4   = lane >> 4;
    const int rbase = blockIdx.x * 128 + wv * 32;

    const int r0 = min(rbase + l15,      NV - 1);
    const int r1 = min(rbase + 16 + l15, NV - 1);
    const float* xp0 = X + (size_t)r0 * KIN + l4 * 8;
    const float* xp1 = X + (size_t)r1 * KIN + l4 * 8;
    const unsigned short* wp = Wb + (size_t)l15 * KIN + l4 * 8;

    f32x4 acc[2][4];
#pragma unroll
    for (int t = 0; t < 2; ++t)
#pragma unroll
        for (int g = 0; g < 4; ++g)
            acc[t][g] = (f32x4){0.f, 0.f, 0.f, 0.f};

#pragma unroll
    for (int s = 0; s < 8; ++s) {
        const int k0 = s * 32;
        const float4 a0lo = *(const float4*)(xp0 + k0);
        const float4 a0hi = *(const float4*)(xp0 + k0 + 4);
        const float4 a1lo = *(const float4*)(xp1 + k0);
        const float4 a1hi = *(const float4*)(xp1 + k0 + 4);
        short8 b[4];
#pragma unroll
        for (int g = 0; g < 4; ++g)
            b[g] = *(const short8*)(wp + (size_t)g * 16 * KIN + k0);
        const short8 a0 = pack8(a0lo, a0hi);
        const short8 a1 = pack8(a1lo, a1hi);
#pragma unroll
        for (int g = 0; g < 4; ++g) {
            acc[0][g] = __builtin_amdgcn_mfma_f32_16x16x32_bf16(a0, b[g], acc[0][g], 0, 0, 0);
            acc[1][g] = __builtin_amdgcn_mfma_f32_16x16x32_bf16(a1, b[g], acc[1][g], 0, 0, 0);
        }
    }

#pragma unroll
    for (int t = 0; t < 2; ++t)
#pragma unroll
        for (int i = 0; i < 4; ++i) {
            const int r = rbase + t * 16 + l4 * 4 + i;
            if (r < NV) {
#pragma unroll
                for (int g = 0; g < 4; ++g)
                    Xpb[(size_t)r * KOUT + g * 16 + l15] = f2bf(acc[t][g][i]);
            }
        }
}

// ---------------------------------------------------------------------------
// Per-block LDS histogram of BOTH bucket keys -> count matrix
// ---------------------------------------------------------------------------
__global__ __launch_bounds__(256) void k_hist(const int* __restrict__ v_idx,
                                              const int* __restrict__ e_idx,
                                              int* __restrict__ mat) {
    __shared__ int h[NBINS];
    const int b = blockIdx.x, tid = threadIdx.x;
    for (int i = tid; i < NBINS; i += 256) h[i] = 0;
    __syncthreads();
    const int base = b * CHUNK;
    for (int i = tid; i < CHUNK; i += 256) {
        atomicAdd(&h[e_idx[base + i] >> 6], 1);
        atomicAdd(&h[NBE + (v_idx[base + i] >> 6)], 1);
    }
    __syncthreads();
    for (int j = tid; j < NBINS; j += 256) mat[j * NB + b] = h[j];
}

// ---------------------------------------------------------------------------
// 3-kernel exclusive scan of mat[LSCAN]
// ---------------------------------------------------------------------------
__global__ __launch_bounds__(1024) void k_scan1(int* __restrict__ mat,
                                                int* __restrict__ bsum) {
    __shared__ int buf[1024];
    const int tid = threadIdx.x;
    const int i = blockIdx.x * 1024 + tid;
    const int v = (i < LSCAN) ? mat[i] : 0;
    buf[tid] = v;
    __syncthreads();
    for (int d = 1; d < 1024; d <<= 1) {
        int t = (tid >= d) ? buf[tid - d] : 0;
        __syncthreads();
        buf[tid] += t;
        __syncthreads();
    }
    if (i < LSCAN) mat[i] = buf[tid] - v;
    if (tid == 1023) bsum[blockIdx.x] = buf[1023];
}

__global__ __launch_bounds__(1024) void k_scan2(int* __restrict__ bsum) {
    __shared__ int buf[1024];
    const int tid = threadIdx.x;
    const int v = (tid < NBLK_SCAN) ? bsum[tid] : 0;
    buf[tid] = v;
    __syncthreads();
    for (int d = 1; d < 1024; d <<= 1) {
        int t = (tid >= d) ? buf[tid - d] : 0;
        __syncthreads();
        buf[tid] += t;
        __syncthreads();
    }
    if (tid < NBLK_SCAN) bsum[tid] = buf[tid] - v;
}

__global__ __launch_bounds__(1024) void k_scan3(int* __restrict__ mat,
                                                const int* __restrict__ bsum) {
    const int i = blockIdx.x * 1024 + threadIdx.x;
    if (i < LSCAN) mat[i] += bsum[blockIdx.x];
}

// ---------------------------------------------------------------------------
// Fused partition: ONE pass over (v_idx, e_idx) writes BOTH bucket-ordered
// arrays. LDS cursors from the scanned matrix; no global atomics.
//   partE[p] = v | ((e&63)<<17)      partV[p] = e | ((v&63)<<17)
// ---------------------------------------------------------------------------
__global__ __launch_bounds__(256) void k_partition2(const int* __restrict__ v_idx,
                                                    const int* __restrict__ e_idx,
                                                    const int* __restrict__ mat,
                                                    unsigned* __restrict__ partE,
                                                    unsigned* __restrict__ partV) {
    __shared__ int curE[NBE];
    __shared__ int curV[NBV];
    const int b = blockIdx.x, tid = threadIdx.x;
    for (int j = tid; j < NBE; j += 256) curE[j] = mat[j * NB + b];
    for (int j = tid; j < NBV; j += 256) curV[j] = mat[(NBE + j) * NB + b] - NNZ;
    __syncthreads();
    const int base = b * CHUNK;
    for (int i = tid; i < CHUNK; i += 256) {
        const int v = v_idx[base + i];
        const int e = e_idx[base + i];
        const int pE = atomicAdd(&curE[e >> 6], 1);
        partE[pE] = (unsigned)v | ((unsigned)(e & 63) << 17);
        const int pV = atomicAdd(&curV[v >> 6], 1);
        partV[pV] = (unsigned)e | ((unsigned)(v & 63) << 17);
    }
}

// ---------------------------------------------------------------------------
// Per-bucket counting sort -> CSR offsets + ordered adj (T = int or u16)
// ---------------------------------------------------------------------------
template <typename T>
__global__ __launch_bounds__(256) void k_buildcsr(const unsigned* __restrict__ part,
                                                  const int* __restrict__ mat,
                                                  int matOff, int sub,
                                                  int* __restrict__ offOut,
                                                  T* __restrict__ adj,
                                                  int nMajor) {
    const int b = blockIdx.x;
    const int tid = threadIdx.x;
    const int base = mat[matOff + b * NB] - sub;
    const int end  = (b == (int)gridDim.x - 1) ? NNZ : (mat[matOff + (b + 1) * NB] - sub);
    const int nb = end - base;
    const int k0 = b << 6;

    __shared__ int hist[64], cur[64];
    if (tid < 64) hist[tid] = 0;
    __syncthreads();

    for (int i = tid; i < nb; i += 256)
        atomicAdd(&hist[(part[base + i] >> 17) & 63], 1);
    __syncthreads();

    if (tid == 0) {
        int s = 0;
        for (int k = 0; k < 64; ++k) {
            int h = hist[k];
            hist[k] = s;
            cur[k] = s;
            s += h;
        }
    }
    __syncthreads();

    const int lim = min(64, nMajor - k0);
    if (tid < lim) offOut[k0 + tid] = base + hist[tid];
    if (b == 0 && tid == 0) offOut[nMajor] = NNZ;

    for (int i = tid; i < nb; i += 256) {
        const unsigned u = part[base + i];
        const int lk = (u >> 17) & 63;
        adj[base + atomicAdd(&cur[lk], 1)] = (T)(u & 0x1FFFFu);
    }
}

// ---------------------------------------------------------------------------
// Stage 1 (pull, quarter-wave): one wave per edge; lane -> 4 channels (uint2),
// 16 lanes/row, 4 entries per instruction round. bf16 out.
// ---------------------------------------------------------------------------
__global__ __launch_bounds__(256) void k_gatherE(const unsigned short* __restrict__ Xpb,
                                                 const int* __restrict__ offE,
                                                 const int* __restrict__ adj,
                                                 const float* __restrict__ degE,
                                                 const float* __restrict__ Wdiag,
                                                 unsigned short* __restrict__ Xeb) {
    const int wave = (blockIdx.x * 256 + threadIdx.x) >> 6;
    const int lane = threadIdx.x & 63;
    const int q    = lane >> 4;          // quarter 0..3
    const int sl   = lane & 15;          // channel group: ch 4*sl..+3
    if (wave >= NE) return;
    const int b = offE[wave];
    const int e = offE[wave + 1];
    float a0 = 0.f, a1 = 0.f, a2 = 0.f, a3 = 0.f;
    for (int base = b; base < e; base += 64) {
        const int m = min(64, e - base);
        const int vi = (base + lane < e) ? adj[base + lane] : 0;
        const int nf = m >> 2;           // full 4-entry rounds
        int t = 0;
        for (; t + 4 <= nf; t += 4) {
            uint2 u[4];
#pragma unroll
            for (int z = 0; z < 4; ++z) {
                const int idx = __shfl(vi, 4 * (t + z) + q, 64);
                u[z] = *(const uint2*)&Xpb[(size_t)idx * KOUT + 4 * sl];
            }
#pragma unroll
            for (int z = 0; z < 4; ++z) {
                a0 += bf2f_lo(u[z].x); a1 += bf2f_hi(u[z].x);
                a2 += bf2f_lo(u[z].y); a3 += bf2f_hi(u[z].y);
            }
        }
        for (; t < nf; ++t) {
            const int idx = __shfl(vi, 4 * t + q, 64);
            const uint2 u = *(const uint2*)&Xpb[(size_t)idx * KOUT + 4 * sl];
            a0 += bf2f_lo(u.x); a1 += bf2f_hi(u.x);
            a2 += bf2f_lo(u.y); a3 += bf2f_hi(u.y);
        }
        if (m & 3) {
            const int src = nf * 4 + q;
            const int idx = __shfl(vi, src & 63, 64);
            const uint2 u = *(const uint2*)&Xpb[(size_t)idx * KOUT + 4 * sl];
            if (src < m) {
                a0 += bf2f_lo(u.x); a1 += bf2f_hi(u.x);
                a2 += bf2f_lo(u.y); a3 += bf2f_hi(u.y);
            }
        }
    }
    a0 += __shfl_xor(a0, 16, 64); a0 += __shfl_xor(a0, 32, 64);
    a1 += __shfl_xor(a1, 16, 64); a1 += __shfl_xor(a1, 32, 64);
    a2 += __shfl_xor(a2, 16, 64); a2 += __shfl_xor(a2, 32, 64);
    a3 += __shfl_xor(a3, 16, 64); a3 += __shfl_xor(a3, 32, 64);
    if (q == 0) {
        const float s = degE[wave] * Wdiag[wave];
        uint2 pk;
        pk.x = (unsigned)f2bf(a0 * s) | ((unsigned)f2bf(a1 * s) << 16);
        pk.y = (unsigned)f2bf(a2 * s) | ((unsigned)f2bf(a3 * s) << 16);
        *(uint2*)&Xeb[(size_t)wave * KOUT + 4 * sl] = pk;
    }
}

// ---------------------------------------------------------------------------
// Stage 2 (pull, quarter-wave): one wave per vertex; u16 adjacency; f32 out.
// ---------------------------------------------------------------------------
__global__ __launch_bounds__(256) void k_gatherV(const unsigned short* __restrict__ Xeb,
                                                 const int* __restrict__ offV,
                                                 const unsigned short* __restrict__ adj,
                                                 const float* __restrict__ degV,
                                                 float* __restrict__ out) {
    const int wave = (blockIdx.x * 256 + threadIdx.x) >> 6;
    const int lane = threadIdx.x & 63;
    const int q    = lane >> 4;
    const int sl   = lane & 15;
    if (wave >= NV) return;
    const int b = offV[wave];
    const int e = offV[wave + 1];
    float a0 = 0.f, a1 = 0.f, a2 = 0.f, a3 = 0.f;
    for (int base = b; base < e; base += 64) {
        const int m = min(64, e - base);
        const int ei = (base + lane < e) ? (int)adj[base + lane] : 0;
        const int nf = m >> 2;
        int t = 0;
        for (; t + 4 <= nf; t += 4) {
            uint2 u[4];
#pragma unroll
            for (int z = 0; z < 4; ++z) {
                const int idx = __shfl(ei, 4 * (t + z) + q, 64);
                u[z] = *(const uint2*)&Xeb[(size_t)idx * KOUT + 4 * sl];
            }
#pragma unroll
            for (int z = 0; z < 4; ++z) {
                a0 += bf2f_lo(u[z].x); a1 += bf2f_hi(u[z].x);
                a2 += bf2f_lo(u[z].y); a3 += bf2f_hi(u[z].y);
            }
        }
        for (; t < nf; ++t) {
            const int idx = __shfl(ei, 4 * t + q, 64);
            const uint2 u = *(const uint2*)&Xeb[(size_t)idx * KOUT + 4 * sl];
            a0 += bf2f_lo(u.x); a1 += bf2f_hi(u.x);
            a2 += bf2f_lo(u.y); a3 += bf2f_hi(u.y);
        }
        if (m & 3) {
            const int src = nf * 4 + q;
            const int idx = __shfl(ei, src & 63, 64);
            const uint2 u = *(const uint2*)&Xeb[(size_t)idx * KOUT + 4 * sl];
            if (src < m) {
                a0 += bf2f_lo(u.x); a1 += bf2f_hi(u.x);
                a2 += bf2f_lo(u.y); a3 += bf2f_hi(u.y);
            }
        }
    }
    a0 += __shfl_xor(a0, 16, 64); a0 += __shfl_xor(a0, 32, 64);
    a1 += __shfl_xor(a1, 16, 64); a1 += __shfl_xor(a1, 32, 64);
    a2 += __shfl_xor(a2, 16, 64); a2 += __shfl_xor(a2, 32, 64);
    a3 += __shfl_xor(a3, 16, 64); a3 += __shfl_xor(a3, 32, 64);
    if (q == 0) {
        const float s = degV[wave];
        *(float4*)&out[(size_t)wave * KOUT + 4 * sl] =
            make_float4(a0 * s, a1 * s, a2 * s, a3 * s);
    }
}

extern "C" void kernel_launch(void* const* d_in, const int* in_sizes, int n_in,
                              void* d_out, int out_size, void* d_ws, size_t ws_size,
                              hipStream_t stream) {
    const float* X     = (const float*)d_in[0];
    const float* W     = (const float*)d_in[1];
    const float* degE  = (const float*)d_in[2];
    const float* degV  = (const float*)d_in[3];
    const float* Wdiag = (const float*)d_in[4];
    const int*   v_idx = (const int*)d_in[5];
    const int*   e_idx = (const int*)d_in[6];
    float* out = (float*)d_out;

    // Workspace (~62 MB). adjV aliases partE (dead after buildcsrE).
    unsigned short* Xpb  = (unsigned short*)d_ws;             // NV*KOUT bf16 (12.8 MB)
    unsigned short* Xeb  = Xpb + (size_t)NV * KOUT;           // NE*KOUT bf16 (6.4 MB)
    unsigned*       partE = (unsigned*)(Xeb + (size_t)NE * KOUT); // NNZ u32
    unsigned*       partV = partE + NNZ;                      // NNZ u32
    int*            adjE  = (int*)(partV + NNZ);              // NNZ int
    int*            offE  = adjE + NNZ;                       // NE+1
    int*            offV  = offE + (NE + 1);                  // NV+1
    int*            mat   = offV + (NV + 1);                  // LSCAN
    int*            bsum  = mat + LSCAN;                      // NBLK_SCAN
    unsigned short* Wb    = (unsigned short*)(bsum + ((NBLK_SCAN + 3) & ~3)); // 32 KB
    unsigned short* adjV  = (unsigned short*)partE;           // NNZ u16 (alias)

    k_wb<<<(KIN * KOUT) / 256, 256, 0, stream>>>(W, Wb);
    k_project<<<(NV + 127) / 128, 256, 0, stream>>>(X, Wb, Xpb);

    k_hist<<<NB, 256, 0, stream>>>(v_idx, e_idx, mat);
    k_scan1<<<NBLK_SCAN, 1024, 0, stream>>>(mat, bsum);
    k_scan2<<<1, 1024, 0, stream>>>(bsum);
    k_scan3<<<NBLK_SCAN, 1024, 0, stream>>>(mat, bsum);

    // One fused pass writes both bucket-ordered arrays
    k_partition2<<<NB, 256, 0, stream>>>(v_idx, e_idx, mat, partE, partV);

    // ---- Edge side: CSR(int adjE) -> gather   [partE dead after buildcsr]
    k_buildcsr<int><<<NBE, 256, 0, stream>>>(partE, mat, 0, 0, offE, adjE, NE);
    k_gatherE<<<(NE * 64) / 256, 256, 0, stream>>>(Xpb, offE, adjE, degE, Wdiag, Xeb);

    // ---- Vertex side: CSR(u16 adjV, aliases partE) -> gather
    k_buildcsr<unsigned short><<<NBV, 256, 0, stream>>>(partV, mat, NBE * NB, NNZ, offV, adjV, NV);
    k_gatherV<<<(NV * 64) / 256, 256, 0, stream>>>(Xeb, offV, adjV, degV, out);
}

// Round 12
// 267.824 us; speedup vs baseline: 10.5032x; 1.0802x over previous
//
#include <hip/hip_runtime.h>

#define NV   100000
#define NE   50000
#define NNZ  3200000
#define KIN  256
#define KOUT 64

#define NB    256                  // partition/hist blocks (NNZ = 256*12500, 1 block/CU)
#define CHUNK (NNZ / NB)           // 12500
#define NBE   782                  // ceil(NE/64) edge buckets
#define NBV   1563                 // ceil(NV/64) vertex buckets
#define NBINS (NBE + NBV)          // 2345
#define LSCAN (NBINS * NB)         // 600320
#define NBLK_SCAN ((LSCAN + 1023) / 1024)   // 587 (must stay <= 1024 for k_scan2)

typedef short short8 __attribute__((ext_vector_type(8)));
typedef float f32x4  __attribute__((ext_vector_type(4)));

__device__ __forceinline__ unsigned short f2bf(float f) {
    union { float f; unsigned u; } c{f};
    const unsigned lsb = (c.u >> 16) & 1u;
    return (unsigned short)((c.u + 0x7FFFu + lsb) >> 16);
}
__device__ __forceinline__ float bf2f_lo(unsigned u) {
    union { unsigned u; float f; } c{u << 16};
    return c.f;
}
__device__ __forceinline__ float bf2f_hi(unsigned u) {
    union { unsigned u; float f; } c{u & 0xFFFF0000u};
    return c.f;
}
__device__ __forceinline__ short8 pack8(const float4 lo, const float4 hi) {
    short8 r;
    r[0] = (short)f2bf(lo.x); r[1] = (short)f2bf(lo.y);
    r[2] = (short)f2bf(lo.z); r[3] = (short)f2bf(lo.w);
    r[4] = (short)f2bf(hi.x); r[5] = (short)f2bf(hi.y);
    r[6] = (short)f2bf(hi.z); r[7] = (short)f2bf(hi.w);
    return r;
}

// ---------------------------------------------------------------------------
// One-off: Wb[o][k] = bf16(W[o][k])
// ---------------------------------------------------------------------------
__global__ __launch_bounds__(256) void k_wb(const float* __restrict__ W,
                                            unsigned short* __restrict__ Wb) {
    const int i = blockIdx.x * 256 + threadIdx.x;
    Wb[i] = f2bf(W[i]);
}

// ---------------------------------------------------------------------------
// Kernel 1: zero-LDS bf16 MFMA GEMM (round-10, verified absmax 1.0)
// ---------------------------------------------------------------------------
__global__ __launch_bounds__(256) void k_project(const float* __restrict__ X,
                                                 const unsigned short* __restrict__ Wb,
                                                 unsigned short* __restrict__ Xpb) {
    const int tid  = threadIdx.x;
    const int lane = tid & 63;
    const int wv   = tid >> 6;
    const int l15  = lane & 15;
    const int l4   = lane >> 4;
    const int rbase = blockIdx.x * 128 + wv * 32;

    const int r0 = min(rbase + l15,      NV - 1);
    const int r1 = min(rbase + 16 + l15, NV - 1);
    const float* xp0 = X + (size_t)r0 * KIN + l4 * 8;
    const float* xp1 = X + (size_t)r1 * KIN + l4 * 8;
    const unsigned short* wp = Wb + (size_t)l15 * KIN + l4 * 8;

    f32x4 acc[2][4];
#pragma unroll
    for (int t = 0; t < 2; ++t)
#pragma unroll
        for (int g = 0; g < 4; ++g)
            acc[t][g] = (f32x4){0.f, 0.f, 0.f, 0.f};

#pragma unroll
    for (int s = 0; s < 8; ++s) {
        const int k0 = s * 32;
        const float4 a0lo = *(const float4*)(xp0 + k0);
        const float4 a0hi = *(const float4*)(xp0 + k0 + 4);
        const float4 a1lo = *(const float4*)(xp1 + k0);
        const float4 a1hi = *(const float4*)(xp1 + k0 + 4);
        short8 b[4];
#pragma unroll
        for (int g = 0; g < 4; ++g)
            b[g] = *(const short8*)(wp + (size_t)g * 16 * KIN + k0);
        const short8 a0 = pack8(a0lo, a0hi);
        const short8 a1 = pack8(a1lo, a1hi);
#pragma unroll
        for (int g = 0; g < 4; ++g) {
            acc[0][g] = __builtin_amdgcn_mfma_f32_16x16x32_bf16(a0, b[g], acc[0][g], 0, 0, 0);
            acc[1][g] = __builtin_amdgcn_mfma_f32_16x16x32_bf16(a1, b[g], acc[1][g], 0, 0, 0);
        }
    }

#pragma unroll
    for (int t = 0; t < 2; ++t)
#pragma unroll
        for (int i = 0; i < 4; ++i) {
            const int r = rbase + t * 16 + l4 * 4 + i;
            if (r < NV) {
#pragma unroll
                for (int g = 0; g < 4; ++g)
                    Xpb[(size_t)r * KOUT + g * 16 + l15] = f2bf(acc[t][g][i]);
            }
        }
}

// ---------------------------------------------------------------------------
// Per-block LDS histogram of BOTH bucket keys -> count matrix (1024 thr)
// ---------------------------------------------------------------------------
__global__ __launch_bounds__(1024) void k_hist(const int* __restrict__ v_idx,
                                               const int* __restrict__ e_idx,
                                               int* __restrict__ mat) {
    __shared__ int h[NBINS];
    const int b = blockIdx.x, tid = threadIdx.x;
    for (int i = tid; i < NBINS; i += 1024) h[i] = 0;
    __syncthreads();
    const int base = b * CHUNK;
    for (int i = tid; i < CHUNK; i += 1024) {
        atomicAdd(&h[e_idx[base + i] >> 6], 1);
        atomicAdd(&h[NBE + (v_idx[base + i] >> 6)], 1);
    }
    __syncthreads();
    for (int j = tid; j < NBINS; j += 1024) mat[j * NB + b] = h[j];
}

// ---------------------------------------------------------------------------
// 3-kernel exclusive scan of mat[LSCAN]
// ---------------------------------------------------------------------------
__global__ __launch_bounds__(1024) void k_scan1(int* __restrict__ mat,
                                                int* __restrict__ bsum) {
    __shared__ int buf[1024];
    const int tid = threadIdx.x;
    const int i = blockIdx.x * 1024 + tid;
    const int v = (i < LSCAN) ? mat[i] : 0;
    buf[tid] = v;
    __syncthreads();
    for (int d = 1; d < 1024; d <<= 1) {
        int t = (tid >= d) ? buf[tid - d] : 0;
        __syncthreads();
        buf[tid] += t;
        __syncthreads();
    }
    if (i < LSCAN) mat[i] = buf[tid] - v;
    if (tid == 1023) bsum[blockIdx.x] = buf[1023];
}

__global__ __launch_bounds__(1024) void k_scan2(int* __restrict__ bsum) {
    __shared__ int buf[1024];
    const int tid = threadIdx.x;
    const int v = (tid < NBLK_SCAN) ? bsum[tid] : 0;
    buf[tid] = v;
    __syncthreads();
    for (int d = 1; d < 1024; d <<= 1) {
        int t = (tid >= d) ? buf[tid - d] : 0;
        __syncthreads();
        buf[tid] += t;
        __syncthreads();
    }
    if (tid < NBLK_SCAN) bsum[tid] = buf[tid] - v;
}

__global__ __launch_bounds__(1024) void k_scan3(int* __restrict__ mat,
                                                const int* __restrict__ bsum) {
    const int i = blockIdx.x * 1024 + threadIdx.x;
    if (i < LSCAN) mat[i] += bsum[blockIdx.x];
}

// ---------------------------------------------------------------------------
// Fused partition (1024 thr): ONE pass writes BOTH bucket-ordered arrays.
//   partE[p] = v | ((e&63)<<17)      partV[p] = e | ((v&63)<<17)
// ---------------------------------------------------------------------------
__global__ __launch_bounds__(1024) void k_partition2(const int* __restrict__ v_idx,
                                                     const int* __restrict__ e_idx,
                                                     const int* __restrict__ mat,
                                                     unsigned* __restrict__ partE,
                                                     unsigned* __restrict__ partV) {
    __shared__ int curE[NBE];
    __shared__ int curV[NBV];
    const int b = blockIdx.x, tid = threadIdx.x;
    for (int j = tid; j < NBE; j += 1024) curE[j] = mat[j * NB + b];
    for (int j = tid; j < NBV; j += 1024) curV[j] = mat[(NBE + j) * NB + b] - NNZ;
    __syncthreads();
    const int base = b * CHUNK;
    for (int i = tid; i < CHUNK; i += 1024) {
        const int v = v_idx[base + i];
        const int e = e_idx[base + i];
        const int pE = atomicAdd(&curE[e >> 6], 1);
        partE[pE] = (unsigned)v | ((unsigned)(e & 63) << 17);
        const int pV = atomicAdd(&curV[v >> 6], 1);
        partV[pV] = (unsigned)e | ((unsigned)(v & 63) << 17);
    }
}

// ---------------------------------------------------------------------------
// Per-bucket counting sort -> CSR offsets + ordered adj (T = int or u16)
// ---------------------------------------------------------------------------
template <typename T>
__global__ __launch_bounds__(256) void k_buildcsr(const unsigned* __restrict__ part,
                                                  const int* __restrict__ mat,
                                                  int matOff, int sub,
                                                  int* __restrict__ offOut,
                                                  T* __restrict__ adj,
                                                  int nMajor) {
    const int b = blockIdx.x;
    const int tid = threadIdx.x;
    const int base = mat[matOff + b * NB] - sub;
    const int end  = (b == (int)gridDim.x - 1) ? NNZ : (mat[matOff + (b + 1) * NB] - sub);
    const int nb = end - base;
    const int k0 = b << 6;

    __shared__ int hist[64], cur[64];
    if (tid < 64) hist[tid] = 0;
    __syncthreads();

    for (int i = tid; i < nb; i += 256)
        atomicAdd(&hist[(part[base + i] >> 17) & 63], 1);
    __syncthreads();

    if (tid == 0) {
        int s = 0;
        for (int k = 0; k < 64; ++k) {
            int h = hist[k];
            hist[k] = s;
            cur[k] = s;
            s += h;
        }
    }
    __syncthreads();

    const int lim = min(64, nMajor - k0);
    if (tid < lim) offOut[k0 + tid] = base + hist[tid];
    if (b == 0 && tid == 0) offOut[nMajor] = NNZ;

    for (int i = tid; i < nb; i += 256) {
        const unsigned u = part[base + i];
        const int lk = (u >> 17) & 63;
        adj[base + atomicAdd(&cur[lk], 1)] = (T)(u & 0x1FFFFu);
    }
}

// ---------------------------------------------------------------------------
// Stage 1 (pull, quarter-wave): one wave per edge; lane -> 4 channels (uint2).
// ---------------------------------------------------------------------------
__global__ __launch_bounds__(256) void k_gatherE(const unsigned short* __restrict__ Xpb,
                                                 const int* __restrict__ offE,
                                                 const int* __restrict__ adj,
                                                 const float* __restrict__ degE,
                                                 const float* __restrict__ Wdiag,
                                                 unsigned short* __restrict__ Xeb) {
    const int wave = (blockIdx.x * 256 + threadIdx.x) >> 6;
    const int lane = threadIdx.x & 63;
    const int q    = lane >> 4;
    const int sl   = lane & 15;
    if (wave >= NE) return;
    const int b = offE[wave];
    const int e = offE[wave + 1];
    float a0 = 0.f, a1 = 0.f, a2 = 0.f, a3 = 0.f;
    for (int base = b; base < e; base += 64) {
        const int m = min(64, e - base);
        const int vi = (base + lane < e) ? adj[base + lane] : 0;
        const int nf = m >> 2;
        int t = 0;
        for (; t + 4 <= nf; t += 4) {
            uint2 u[4];
#pragma unroll
            for (int z = 0; z < 4; ++z) {
                const int idx = __shfl(vi, 4 * (t + z) + q, 64);
                u[z] = *(const uint2*)&Xpb[(size_t)idx * KOUT + 4 * sl];
            }
#pragma unroll
            for (int z = 0; z < 4; ++z) {
                a0 += bf2f_lo(u[z].x); a1 += bf2f_hi(u[z].x);
                a2 += bf2f_lo(u[z].y); a3 += bf2f_hi(u[z].y);
            }
        }
        for (; t < nf; ++t) {
            const int idx = __shfl(vi, 4 * t + q, 64);
            const uint2 u = *(const uint2*)&Xpb[(size_t)idx * KOUT + 4 * sl];
            a0 += bf2f_lo(u.x); a1 += bf2f_hi(u.x);
            a2 += bf2f_lo(u.y); a3 += bf2f_hi(u.y);
        }
        if (m & 3) {
            const int src = nf * 4 + q;
            const int idx = __shfl(vi, src & 63, 64);
            const uint2 u = *(const uint2*)&Xpb[(size_t)idx * KOUT + 4 * sl];
            if (src < m) {
                a0 += bf2f_lo(u.x); a1 += bf2f_hi(u.x);
                a2 += bf2f_lo(u.y); a3 += bf2f_hi(u.y);
            }
        }
    }
    a0 += __shfl_xor(a0, 16, 64); a0 += __shfl_xor(a0, 32, 64);
    a1 += __shfl_xor(a1, 16, 64); a1 += __shfl_xor(a1, 32, 64);
    a2 += __shfl_xor(a2, 16, 64); a2 += __shfl_xor(a2, 32, 64);
    a3 += __shfl_xor(a3, 16, 64); a3 += __shfl_xor(a3, 32, 64);
    if (q == 0) {
        const float s = degE[wave] * Wdiag[wave];
        uint2 pk;
        pk.x = (unsigned)f2bf(a0 * s) | ((unsigned)f2bf(a1 * s) << 16);
        pk.y = (unsigned)f2bf(a2 * s) | ((unsigned)f2bf(a3 * s) << 16);
        *(uint2*)&Xeb[(size_t)wave * KOUT + 4 * sl] = pk;
    }
}

// ---------------------------------------------------------------------------
// Stage 2 (pull, quarter-wave): one wave per vertex; u16 adjacency; f32 out.
// ---------------------------------------------------------------------------
__global__ __launch_bounds__(256) void k_gatherV(const unsigned short* __restrict__ Xeb,
                                                 const int* __restrict__ offV,
                                                 const unsigned short* __restrict__ adj,
                                                 const float* __restrict__ degV,
                                                 float* __restrict__ out) {
    const int wave = (blockIdx.x * 256 + threadIdx.x) >> 6;
    const int lane = threadIdx.x & 63;
    const int q    = lane >> 4;
    const int sl   = lane & 15;
    if (wave >= NV) return;
    const int b = offV[wave];
    const int e = offV[wave + 1];
    float a0 = 0.f, a1 = 0.f, a2 = 0.f, a3 = 0.f;
    for (int base = b; base < e; base += 64) {
        const int m = min(64, e - base);
        const int ei = (base + lane < e) ? (int)adj[base + lane] : 0;
        const int nf = m >> 2;
        int t = 0;
        for (; t + 4 <= nf; t += 4) {
            uint2 u[4];
#pragma unroll
            for (int z = 0; z < 4; ++z) {
                const int idx = __shfl(ei, 4 * (t + z) + q, 64);
                u[z] = *(const uint2*)&Xeb[(size_t)idx * KOUT + 4 * sl];
            }
#pragma unroll
            for (int z = 0; z < 4; ++z) {
                a0 += bf2f_lo(u[z].x); a1 += bf2f_hi(u[z].x);
                a2 += bf2f_lo(u[z].y); a3 += bf2f_hi(u[z].y);
            }
        }
        for (; t < nf; ++t) {
            const int idx = __shfl(ei, 4 * t + q, 64);
            const uint2 u = *(const uint2*)&Xeb[(size_t)idx * KOUT + 4 * sl];
            a0 += bf2f_lo(u.x); a1 += bf2f_hi(u.x);
            a2 += bf2f_lo(u.y); a3 += bf2f_hi(u.y);
        }
        if (m & 3) {
            const int src = nf * 4 + q;
            const int idx = __shfl(ei, src & 63, 64);
            const uint2 u = *(const uint2*)&Xeb[(size_t)idx * KOUT + 4 * sl];
            if (src < m) {
                a0 += bf2f_lo(u.x); a1 += bf2f_hi(u.x);
                a2 += bf2f_lo(u.y); a3 += bf2f_hi(u.y);
            }
        }
    }
    a0 += __shfl_xor(a0, 16, 64); a0 += __shfl_xor(a0, 32, 64);
    a1 += __shfl_xor(a1, 16, 64); a1 += __shfl_xor(a1, 32, 64);
    a2 += __shfl_xor(a2, 16, 64); a2 += __shfl_xor(a2, 32, 64);
    a3 += __shfl_xor(a3, 16, 64); a3 += __shfl_xor(a3, 32, 64);
    if (q == 0) {
        const float s = degV[wave];
        *(float4*)&out[(size_t)wave * KOUT + 4 * sl] =
            make_float4(a0 * s, a1 * s, a2 * s, a3 * s);
    }
}

extern "C" void kernel_launch(void* const* d_in, const int* in_sizes, int n_in,
                              void* d_out, int out_size, void* d_ws, size_t ws_size,
                              hipStream_t stream) {
    const float* X     = (const float*)d_in[0];
    const float* W     = (const float*)d_in[1];
    const float* degE  = (const float*)d_in[2];
    const float* degV  = (const float*)d_in[3];
    const float* Wdiag = (const float*)d_in[4];
    const int*   v_idx = (const int*)d_in[5];
    const int*   e_idx = (const int*)d_in[6];
    float* out = (float*)d_out;

    // Workspace (~60 MB). adjV aliases partE (dead after buildcsrE).
    unsigned short* Xpb  = (unsigned short*)d_ws;             // NV*KOUT bf16 (12.8 MB)
    unsigned short* Xeb  = Xpb + (size_t)NV * KOUT;           // NE*KOUT bf16 (6.4 MB)
    unsigned*       partE = (unsigned*)(Xeb + (size_t)NE * KOUT); // NNZ u32
    unsigned*       partV = partE + NNZ;                      // NNZ u32
    int*            adjE  = (int*)(partV + NNZ);              // NNZ int
    int*            offE  = adjE + NNZ;                       // NE+1
    int*            offV  = offE + (NE + 1);                  // NV+1
    int*            mat   = offV + (NV + 1);                  // LSCAN
    int*            bsum  = mat + LSCAN;                      // NBLK_SCAN
    unsigned short* Wb    = (unsigned short*)(bsum + ((NBLK_SCAN + 3) & ~3)); // 32 KB
    unsigned short* adjV  = (unsigned short*)partE;           // NNZ u16 (alias)

    k_wb<<<(KIN * KOUT) / 256, 256, 0, stream>>>(W, Wb);
    k_project<<<(NV + 127) / 128, 256, 0, stream>>>(X, Wb, Xpb);

    k_hist<<<NB, 1024, 0, stream>>>(v_idx, e_idx, mat);
    k_scan1<<<NBLK_SCAN, 1024, 0, stream>>>(mat, bsum);
    k_scan2<<<1, 1024, 0, stream>>>(bsum);
    k_scan3<<<NBLK_SCAN, 1024, 0, stream>>>(mat, bsum);

    // One fused pass writes both bucket-ordered arrays
    k_partition2<<<NB, 1024, 0, stream>>>(v_idx, e_idx, mat, partE, partV);

    // ---- Edge side: CSR(int adjE) -> gather   [partE dead after buildcsr]
    k_buildcsr<int><<<NBE, 256, 0, stream>>>(partE, mat, 0, 0, offE, adjE, NE);
    k_gatherE<<<(NE * 64) / 256, 256, 0, stream>>>(Xpb, offE, adjE, degE, Wdiag, Xeb);

    // ---- Vertex side: CSR(u16 adjV, aliases partE) -> gather
    k_buildcsr<unsigned short><<<NBV, 256, 0, stream>>>(partV, mat, NBE * NB, NNZ, offV, adjV, NV);
    k_gatherV<<<(NV * 64) / 256, 256, 0, stream>>>(Xeb, offV, adjV, degV, out);
}

// Round 13
// 265.551 us; speedup vs baseline: 10.5931x; 1.0086x over previous
//
#include <hip/hip_runtime.h>

#define NV   100000
#define NE   50000
#define NNZ  3200000
#define KIN  256
#define KOUT 64

#define NB    128                  // partition/hist blocks (NNZ = 128*25000 exactly)
#define CHUNK (NNZ / NB)           // 25000
#define NBE   782                  // ceil(NE/64) edge buckets
#define NBV   1563                 // ceil(NV/64) vertex buckets
#define NBINS (NBE + NBV)          // 2345
#define LSCAN (NBINS * NB)         // 300160
#define NBLK_SCAN ((LSCAN + 1023) / 1024)   // 294 (must stay <= 1024 for k_scan2)

typedef short short8 __attribute__((ext_vector_type(8)));
typedef float f32x4  __attribute__((ext_vector_type(4)));

__device__ __forceinline__ unsigned short f2bf(float f) {
    union { float f; unsigned u; } c{f};
    const unsigned lsb = (c.u >> 16) & 1u;
    return (unsigned short)((c.u + 0x7FFFu + lsb) >> 16);
}
__device__ __forceinline__ float bf2f_lo(unsigned u) {
    union { unsigned u; float f; } c{u << 16};
    return c.f;
}
__device__ __forceinline__ float bf2f_hi(unsigned u) {
    union { unsigned u; float f; } c{u & 0xFFFF0000u};
    return c.f;
}
__device__ __forceinline__ short8 pack8(const float4 lo, const float4 hi) {
    short8 r;
    r[0] = (short)f2bf(lo.x); r[1] = (short)f2bf(lo.y);
    r[2] = (short)f2bf(lo.z); r[3] = (short)f2bf(lo.w);
    r[4] = (short)f2bf(hi.x); r[5] = (short)f2bf(hi.y);
    r[6] = (short)f2bf(hi.z); r[7] = (short)f2bf(hi.w);
    return r;
}

// ---------------------------------------------------------------------------
// One-off: Wb[o][k] = bf16(W[o][k])
// ---------------------------------------------------------------------------
__global__ __launch_bounds__(256) void k_wb(const float* __restrict__ W,
                                            unsigned short* __restrict__ Wb) {
    const int i = blockIdx.x * 256 + threadIdx.x;
    Wb[i] = f2bf(W[i]);
}

// ---------------------------------------------------------------------------
// Kernel 1: zero-LDS bf16 MFMA GEMM (round-10, verified absmax 1.0)
// ---------------------------------------------------------------------------
__global__ __launch_bounds__(256) void k_project(const float* __restrict__ X,
                                                 const unsigned short* __restrict__ Wb,
                                                 unsigned short* __restrict__ Xpb) {
    const int tid  = threadIdx.x;
    const int lane = tid & 63;
    const int wv   = tid >> 6;
    const int l15  = lane & 15;
    const int l4   = lane >> 4;
    const int rbase = blockIdx.x * 128 + wv * 32;

    const int r0 = min(rbase + l15,      NV - 1);
    const int r1 = min(rbase + 16 + l15, NV - 1);
    const float* xp0 = X + (size_t)r0 * KIN + l4 * 8;
    const float* xp1 = X + (size_t)r1 * KIN + l4 * 8;
    const unsigned short* wp = Wb + (size_t)l15 * KIN + l4 * 8;

    f32x4 acc[2][4];
#pragma unroll
    for (int t = 0; t < 2; ++t)
#pragma unroll
        for (int g = 0; g < 4; ++g)
            acc[t][g] = (f32x4){0.f, 0.f, 0.f, 0.f};

#pragma unroll
    for (int s = 0; s < 8; ++s) {
        const int k0 = s * 32;
        const float4 a0lo = *(const float4*)(xp0 + k0);
        const float4 a0hi = *(const float4*)(xp0 + k0 + 4);
        const float4 a1lo = *(const float4*)(xp1 + k0);
        const float4 a1hi = *(const float4*)(xp1 + k0 + 4);
        short8 b[4];
#pragma unroll
        for (int g = 0; g < 4; ++g)
            b[g] = *(const short8*)(wp + (size_t)g * 16 * KIN + k0);
        const short8 a0 = pack8(a0lo, a0hi);
        const short8 a1 = pack8(a1lo, a1hi);
#pragma unroll
        for (int g = 0; g < 4; ++g) {
            acc[0][g] = __builtin_amdgcn_mfma_f32_16x16x32_bf16(a0, b[g], acc[0][g], 0, 0, 0);
            acc[1][g] = __builtin_amdgcn_mfma_f32_16x16x32_bf16(a1, b[g], acc[1][g], 0, 0, 0);
        }
    }

#pragma unroll
    for (int t = 0; t < 2; ++t)
#pragma unroll
        for (int i = 0; i < 4; ++i) {
            const int r = rbase + t * 16 + l4 * 4 + i;
            if (r < NV) {
#pragma unroll
                for (int g = 0; g < 4; ++g)
                    Xpb[(size_t)r * KOUT + g * 16 + l15] = f2bf(acc[t][g][i]);
            }
        }
}

// ---------------------------------------------------------------------------
// Per-block LDS histogram of BOTH bucket keys -> count matrix (1024 thr)
// ---------------------------------------------------------------------------
__global__ __launch_bounds__(1024) void k_hist(const int* __restrict__ v_idx,
                                               const int* __restrict__ e_idx,
                                               int* __restrict__ mat) {
    __shared__ int h[NBINS];
    const int b = blockIdx.x, tid = threadIdx.x;
    for (int i = tid; i < NBINS; i += 1024) h[i] = 0;
    __syncthreads();
    const int base = b * CHUNK;
    for (int i = tid; i < CHUNK; i += 1024) {
        atomicAdd(&h[e_idx[base + i] >> 6], 1);
        atomicAdd(&h[NBE + (v_idx[base + i] >> 6)], 1);
    }
    __syncthreads();
    for (int j = tid; j < NBINS; j += 1024) mat[j * NB + b] = h[j];
}

// ---------------------------------------------------------------------------
// 3-kernel exclusive scan of mat[LSCAN]
// ---------------------------------------------------------------------------
__global__ __launch_bounds__(1024) void k_scan1(int* __restrict__ mat,
                                                int* __restrict__ bsum) {
    __shared__ int buf[1024];
    const int tid = threadIdx.x;
    const int i = blockIdx.x * 1024 + tid;
    const int v = (i < LSCAN) ? mat[i] : 0;
    buf[tid] = v;
    __syncthreads();
    for (int d = 1; d < 1024; d <<= 1) {
        int t = (tid >= d) ? buf[tid - d] : 0;
        __syncthreads();
        buf[tid] += t;
        __syncthreads();
    }
    if (i < LSCAN) mat[i] = buf[tid] - v;
    if (tid == 1023) bsum[blockIdx.x] = buf[1023];
}

__global__ __launch_bounds__(1024) void k_scan2(int* __restrict__ bsum) {
    __shared__ int buf[1024];
    const int tid = threadIdx.x;
    const int v = (tid < NBLK_SCAN) ? bsum[tid] : 0;
    buf[tid] = v;
    __syncthreads();
    for (int d = 1; d < 1024; d <<= 1) {
        int t = (tid >= d) ? buf[tid - d] : 0;
        __syncthreads();
        buf[tid] += t;
        __syncthreads();
    }
    if (tid < NBLK_SCAN) bsum[tid] = buf[tid] - v;
}

__global__ __launch_bounds__(1024) void k_scan3(int* __restrict__ mat,
                                                const int* __restrict__ bsum) {
    const int i = blockIdx.x * 1024 + threadIdx.x;
    if (i < LSCAN) mat[i] += bsum[blockIdx.x];
}

// ---------------------------------------------------------------------------
// Fused partition (1024 thr): ONE pass writes BOTH bucket-ordered arrays.
//   partE[p] = v | ((e&63)<<17)      partV[p] = e | ((v&63)<<17)
// NB=128 keeps per-XCD active write lines (16 blk x 2345 lines ~ 2.4 MB)
// inside the 4 MB per-XCD L2 -> cursor lines absorb all run writes.
// ---------------------------------------------------------------------------
__global__ __launch_bounds__(1024) void k_partition2(const int* __restrict__ v_idx,
                                                     const int* __restrict__ e_idx,
                                                     const int* __restrict__ mat,
                                                     unsigned* __restrict__ partE,
                                                     unsigned* __restrict__ partV) {
    __shared__ int curE[NBE];
    __shared__ int curV[NBV];
    const int b = blockIdx.x, tid = threadIdx.x;
    for (int j = tid; j < NBE; j += 1024) curE[j] = mat[j * NB + b];
    for (int j = tid; j < NBV; j += 1024) curV[j] = mat[(NBE + j) * NB + b] - NNZ;
    __syncthreads();
    const int base = b * CHUNK;
    for (int i = tid; i < CHUNK; i += 1024) {
        const int v = v_idx[base + i];
        const int e = e_idx[base + i];
        const int pE = atomicAdd(&curE[e >> 6], 1);
        partE[pE] = (unsigned)v | ((unsigned)(e & 63) << 17);
        const int pV = atomicAdd(&curV[v >> 6], 1);
        partV[pV] = (unsigned)e | ((unsigned)(v & 63) << 17);
    }
}

// ---------------------------------------------------------------------------
// Per-bucket counting sort -> CSR offsets + ordered adj (T = int or u16)
// ---------------------------------------------------------------------------
template <typename T>
__global__ __launch_bounds__(256) void k_buildcsr(const unsigned* __restrict__ part,
                                                  const int* __restrict__ mat,
                                                  int matOff, int sub,
                                                  int* __restrict__ offOut,
                                                  T* __restrict__ adj,
                                                  int nMajor) {
    const int b = blockIdx.x;
    const int tid = threadIdx.x;
    const int base = mat[matOff + b * NB] - sub;
    const int end  = (b == (int)gridDim.x - 1) ? NNZ : (mat[matOff + (b + 1) * NB] - sub);
    const int nb = end - base;
    const int k0 = b << 6;

    __shared__ int hist[64], cur[64];
    if (tid < 64) hist[tid] = 0;
    __syncthreads();

    for (int i = tid; i < nb; i += 256)
        atomicAdd(&hist[(part[base + i] >> 17) & 63], 1);
    __syncthreads();

    if (tid == 0) {
        int s = 0;
        for (int k = 0; k < 64; ++k) {
            int h = hist[k];
            hist[k] = s;
            cur[k] = s;
            s += h;
        }
    }
    __syncthreads();

    const int lim = min(64, nMajor - k0);
    if (tid < lim) offOut[k0 + tid] = base + hist[tid];
    if (b == 0 && tid == 0) offOut[nMajor] = NNZ;

    for (int i = tid; i < nb; i += 256) {
        const unsigned u = part[base + i];
        const int lk = (u >> 17) & 63;
        adj[base + atomicAdd(&cur[lk], 1)] = (T)(u & 0x1FFFFu);
    }
}

// ---------------------------------------------------------------------------
// Stage 1 (pull, quarter-wave): one wave per edge; lane -> 4 channels (uint2).
// ---------------------------------------------------------------------------
__global__ __launch_bounds__(256) void k_gatherE(const unsigned short* __restrict__ Xpb,
                                                 const int* __restrict__ offE,
                                                 const int* __restrict__ adj,
                                                 const float* __restrict__ degE,
                                                 const float* __restrict__ Wdiag,
                                                 unsigned short* __restrict__ Xeb) {
    const int wave = (blockIdx.x * 256 + threadIdx.x) >> 6;
    const int lane = threadIdx.x & 63;
    const int q    = lane >> 4;
    const int sl   = lane & 15;
    if (wave >= NE) return;
    const int b = offE[wave];
    const int e = offE[wave + 1];
    float a0 = 0.f, a1 = 0.f, a2 = 0.f, a3 = 0.f;
    for (int base = b; base < e; base += 64) {
        const int m = min(64, e - base);
        const int vi = (base + lane < e) ? adj[base + lane] : 0;
        const int nf = m >> 2;
        int t = 0;
        for (; t + 4 <= nf; t += 4) {
            uint2 u[4];
#pragma unroll
            for (int z = 0; z < 4; ++z) {
                const int idx = __shfl(vi, 4 * (t + z) + q, 64);
                u[z] = *(const uint2*)&Xpb[(size_t)idx * KOUT + 4 * sl];
            }
#pragma unroll
            for (int z = 0; z < 4; ++z) {
                a0 += bf2f_lo(u[z].x); a1 += bf2f_hi(u[z].x);
                a2 += bf2f_lo(u[z].y); a3 += bf2f_hi(u[z].y);
            }
        }
        for (; t < nf; ++t) {
            const int idx = __shfl(vi, 4 * t + q, 64);
            const uint2 u = *(const uint2*)&Xpb[(size_t)idx * KOUT + 4 * sl];
            a0 += bf2f_lo(u.x); a1 += bf2f_hi(u.x);
            a2 += bf2f_lo(u.y); a3 += bf2f_hi(u.y);
        }
        if (m & 3) {
            const int src = nf * 4 + q;
            const int idx = __shfl(vi, src & 63, 64);
            const uint2 u = *(const uint2*)&Xpb[(size_t)idx * KOUT + 4 * sl];
            if (src < m) {
                a0 += bf2f_lo(u.x); a1 += bf2f_hi(u.x);
                a2 += bf2f_lo(u.y); a3 += bf2f_hi(u.y);
            }
        }
    }
    a0 += __shfl_xor(a0, 16, 64); a0 += __shfl_xor(a0, 32, 64);
    a1 += __shfl_xor(a1, 16, 64); a1 += __shfl_xor(a1, 32, 64);
    a2 += __shfl_xor(a2, 16, 64); a2 += __shfl_xor(a2, 32, 64);
    a3 += __shfl_xor(a3, 16, 64); a3 += __shfl_xor(a3, 32, 64);
    if (q == 0) {
        const float s = degE[wave] * Wdiag[wave];
        uint2 pk;
        pk.x = (unsigned)f2bf(a0 * s) | ((unsigned)f2bf(a1 * s) << 16);
        pk.y = (unsigned)f2bf(a2 * s) | ((unsigned)f2bf(a3 * s) << 16);
        *(uint2*)&Xeb[(size_t)wave * KOUT + 4 * sl] = pk;
    }
}

// ---------------------------------------------------------------------------
// Stage 2 (pull, quarter-wave): one wave per vertex; u16 adjacency; f32 out.
// ---------------------------------------------------------------------------
__global__ __launch_bounds__(256) void k_gatherV(const unsigned short* __restrict__ Xeb,
                                                 const int* __restrict__ offV,
                                                 const unsigned short* __restrict__ adj,
                                                 const float* __restrict__ degV,
                                                 float* __restrict__ out) {
    const int wave = (blockIdx.x * 256 + threadIdx.x) >> 6;
    const int lane = threadIdx.x & 63;
    const int q    = lane >> 4;
    const int sl   = lane & 15;
    if (wave >= NV) return;
    const int b = offV[wave];
    const int e = offV[wave + 1];
    float a0 = 0.f, a1 = 0.f, a2 = 0.f, a3 = 0.f;
    for (int base = b; base < e; base += 64) {
        const int m = min(64, e - base);
        const int ei = (base + lane < e) ? (int)adj[base + lane] : 0;
        const int nf = m >> 2;
        int t = 0;
        for (; t + 4 <= nf; t += 4) {
            uint2 u[4];
#pragma unroll
            for (int z = 0; z < 4; ++z) {
                const int idx = __shfl(ei, 4 * (t + z) + q, 64);
                u[z] = *(const uint2*)&Xeb[(size_t)idx * KOUT + 4 * sl];
            }
#pragma unroll
            for (int z = 0; z < 4; ++z) {
                a0 += bf2f_lo(u[z].x); a1 += bf2f_hi(u[z].x);
                a2 += bf2f_lo(u[z].y); a3 += bf2f_hi(u[z].y);
            }
        }
        for (; t < nf; ++t) {
            const int idx = __shfl(ei, 4 * t + q, 64);
            const uint2 u = *(const uint2*)&Xeb[(size_t)idx * KOUT + 4 * sl];
            a0 += bf2f_lo(u.x); a1 += bf2f_hi(u.x);
            a2 += bf2f_lo(u.y); a3 += bf2f_hi(u.y);
        }
        if (m & 3) {
            const int src = nf * 4 + q;
            const int idx = __shfl(ei, src & 63, 64);
            const uint2 u = *(const uint2*)&Xeb[(size_t)idx * KOUT + 4 * sl];
            if (src < m) {
                a0 += bf2f_lo(u.x); a1 += bf2f_hi(u.x);
                a2 += bf2f_lo(u.y); a3 += bf2f_hi(u.y);
            }
        }
    }
    a0 += __shfl_xor(a0, 16, 64); a0 += __shfl_xor(a0, 32, 64);
    a1 += __shfl_xor(a1, 16, 64); a1 += __shfl_xor(a1, 32, 64);
    a2 += __shfl_xor(a2, 16, 64); a2 += __shfl_xor(a2, 32, 64);
    a3 += __shfl_xor(a3, 16, 64); a3 += __shfl_xor(a3, 32, 64);
    if (q == 0) {
        const float s = degV[wave];
        *(float4*)&out[(size_t)wave * KOUT + 4 * sl] =
            make_float4(a0 * s, a1 * s, a2 * s, a3 * s);
    }
}

extern "C" void kernel_launch(void* const* d_in, const int* in_sizes, int n_in,
                              void* d_out, int out_size, void* d_ws, size_t ws_size,
                              hipStream_t stream) {
    const float* X     = (const float*)d_in[0];
    const float* W     = (const float*)d_in[1];
    const float* degE  = (const float*)d_in[2];
    const float* degV  = (const float*)d_in[3];
    const float* Wdiag = (const float*)d_in[4];
    const int*   v_idx = (const int*)d_in[5];
    const int*   e_idx = (const int*)d_in[6];
    float* out = (float*)d_out;

    // Workspace (~59 MB). adjV aliases partE (dead after buildcsrE).
    unsigned short* Xpb  = (unsigned short*)d_ws;             // NV*KOUT bf16 (12.8 MB)
    unsigned short* Xeb  = Xpb + (size_t)NV * KOUT;           // NE*KOUT bf16 (6.4 MB)
    unsigned*       partE = (unsigned*)(Xeb + (size_t)NE * KOUT); // NNZ u32
    unsigned*       partV = partE + NNZ;                      // NNZ u32
    int*            adjE  = (int*)(partV + NNZ);              // NNZ int
    int*            offE  = adjE + NNZ;                       // NE+1
    int*            offV  = offE + (NE + 1);                  // NV+1
    int*            mat   = offV + (NV + 1);                  // LSCAN
    int*            bsum  = mat + LSCAN;                      // NBLK_SCAN
    unsigned short* Wb    = (unsigned short*)(bsum + ((NBLK_SCAN + 3) & ~3)); // 32 KB
    unsigned short* adjV  = (unsigned short*)partE;           // NNZ u16 (alias)

    k_wb<<<(KIN * KOUT) / 256, 256, 0, stream>>>(W, Wb);
    k_project<<<(NV + 127) / 128, 256, 0, stream>>>(X, Wb, Xpb);

    k_hist<<<NB, 1024, 0, stream>>>(v_idx, e_idx, mat);
    k_scan1<<<NBLK_SCAN, 1024, 0, stream>>>(mat, bsum);
    k_scan2<<<1, 1024, 0, stream>>>(bsum);
    k_scan3<<<NBLK_SCAN, 1024, 0, stream>>>(mat, bsum);

    // One fused pass writes both bucket-ordered arrays
    k_partition2<<<NB, 1024, 0, stream>>>(v_idx, e_idx, mat, partE, partV);

    // ---- Edge side: CSR(int adjE) -> gather   [partE dead after buildcsr]
    k_buildcsr<int><<<NBE, 256, 0, stream>>>(partE, mat, 0, 0, offE, adjE, NE);
    k_gatherE<<<(NE * 64) / 256, 256, 0, stream>>>(Xpb, offE, adjE, degE, Wdiag, Xeb);

    // ---- Vertex side: CSR(u16 adjV, aliases partE) -> gather
    k_buildcsr<unsigned short><<<NBV, 256, 0, stream>>>(partV, mat, NBE * NB, NNZ, offV, adjV, NV);
    k_gatherV<<<(NV * 64) / 256, 256, 0, stream>>>(Xeb, offV, adjV, degV, out);
}

// Round 14
// 243.993 us; speedup vs baseline: 11.5291x; 1.0884x over previous
//
#include <hip/hip_runtime.h>

#define NV   100000
#define NE   50000
#define NNZ  3200000
#define KIN  256
#define KOUT 64

#define NB    128                  // partition/hist blocks (NNZ = 128*25000 exactly)
#define CHUNK (NNZ / NB)           // 25000
#define NBE   782                  // ceil(NE/64) edge buckets
#define NBV   1563                 // ceil(NV/64) vertex buckets
#define NBINS (NBE + NBV)          // 2345
#define LSCAN (NBINS * NB)         // 300160
#define NBLK_SCAN ((LSCAN + 1023) / 1024)   // 294 (<= 1024 for k_scan2)

#define ECAP_E 6144                // E-bucket LDS capacity (mean 4096, +32 sigma)
#define ECAP_V 4096                // V-bucket LDS capacity (mean 2048, +45 sigma)

typedef short short8 __attribute__((ext_vector_type(8)));
typedef float f32x4  __attribute__((ext_vector_type(4)));

__device__ __forceinline__ unsigned short f2bf(float f) {
    union { float f; unsigned u; } c{f};
    const unsigned lsb = (c.u >> 16) & 1u;
    return (unsigned short)((c.u + 0x7FFFu + lsb) >> 16);
}
__device__ __forceinline__ float bf2f_lo(unsigned u) {
    union { unsigned u; float f; } c{u << 16};
    return c.f;
}
__device__ __forceinline__ float bf2f_hi(unsigned u) {
    union { unsigned u; float f; } c{u & 0xFFFF0000u};
    return c.f;
}
__device__ __forceinline__ short8 pack8(const float4 lo, const float4 hi) {
    short8 r;
    r[0] = (short)f2bf(lo.x); r[1] = (short)f2bf(lo.y);
    r[2] = (short)f2bf(lo.z); r[3] = (short)f2bf(lo.w);
    r[4] = (short)f2bf(hi.x); r[5] = (short)f2bf(hi.y);
    r[6] = (short)f2bf(hi.z); r[7] = (short)f2bf(hi.w);
    return r;
}

// ---------------------------------------------------------------------------
// One-off: Wb[o][k] = bf16(W[o][k])
// ---------------------------------------------------------------------------
__global__ __launch_bounds__(256) void k_wb(const float* __restrict__ W,
                                            unsigned short* __restrict__ Wb) {
    const int i = blockIdx.x * 256 + threadIdx.x;
    Wb[i] = f2bf(W[i]);
}

// ---------------------------------------------------------------------------
// Kernel 1: zero-LDS bf16 MFMA GEMM (round-10, verified absmax 1.0)
// ---------------------------------------------------------------------------
__global__ __launch_bounds__(256) void k_project(const float* __restrict__ X,
                                                 const unsigned short* __restrict__ Wb,
                                                 unsigned short* __restrict__ Xpb) {
    const int tid  = threadIdx.x;
    const int lane = tid & 63;
    const int wv   = tid >> 6;
    const int l15  = lane & 15;
    const int l4   = lane >> 4;
    const int rbase = blockIdx.x * 128 + wv * 32;

    const int r0 = min(rbase + l15,      NV - 1);
    const int r1 = min(rbase + 16 + l15, NV - 1);
    const float* xp0 = X + (size_t)r0 * KIN + l4 * 8;
    const float* xp1 = X + (size_t)r1 * KIN + l4 * 8;
    const unsigned short* wp = Wb + (size_t)l15 * KIN + l4 * 8;

    f32x4 acc[2][4];
#pragma unroll
    for (int t = 0; t < 2; ++t)
#pragma unroll
        for (int g = 0; g < 4; ++g)
            acc[t][g] = (f32x4){0.f, 0.f, 0.f, 0.f};

#pragma unroll
    for (int s = 0; s < 8; ++s) {
        const int k0 = s * 32;
        const float4 a0lo = *(const float4*)(xp0 + k0);
        const float4 a0hi = *(const float4*)(xp0 + k0 + 4);
        const float4 a1lo = *(const float4*)(xp1 + k0);
        const float4 a1hi = *(const float4*)(xp1 + k0 + 4);
        short8 b[4];
#pragma unroll
        for (int g = 0; g < 4; ++g)
            b[g] = *(const short8*)(wp + (size_t)g * 16 * KIN + k0);
        const short8 a0 = pack8(a0lo, a0hi);
        const short8 a1 = pack8(a1lo, a1hi);
#pragma unroll
        for (int g = 0; g < 4; ++g) {
            acc[0][g] = __builtin_amdgcn_mfma_f32_16x16x32_bf16(a0, b[g], acc[0][g], 0, 0, 0);
            acc[1][g] = __builtin_amdgcn_mfma_f32_16x16x32_bf16(a1, b[g], acc[1][g], 0, 0, 0);
        }
    }

#pragma unroll
    for (int t = 0; t < 2; ++t)
#pragma unroll
        for (int i = 0; i < 4; ++i) {
            const int r = rbase + t * 16 + l4 * 4 + i;
            if (r < NV) {
#pragma unroll
                for (int g = 0; g < 4; ++g)
                    Xpb[(size_t)r * KOUT + g * 16 + l15] = f2bf(acc[t][g][i]);
            }
        }
}

// ---------------------------------------------------------------------------
// Per-block LDS histogram of BOTH bucket keys -> count matrix (1024 thr)
// ---------------------------------------------------------------------------
__global__ __launch_bounds__(1024) void k_hist(const int* __restrict__ v_idx,
                                               const int* __restrict__ e_idx,
                                               int* __restrict__ mat) {
    __shared__ int h[NBINS];
    const int b = blockIdx.x, tid = threadIdx.x;
    for (int i = tid; i < NBINS; i += 1024) h[i] = 0;
    __syncthreads();
    const int base = b * CHUNK;
    for (int i = tid; i < CHUNK; i += 1024) {
        atomicAdd(&h[e_idx[base + i] >> 6], 1);
        atomicAdd(&h[NBE + (v_idx[base + i] >> 6)], 1);
    }
    __syncthreads();
    for (int j = tid; j < NBINS; j += 1024) mat[j * NB + b] = h[j];
}

// ---------------------------------------------------------------------------
// 3-kernel exclusive scan of mat[LSCAN]
// ---------------------------------------------------------------------------
__global__ __launch_bounds__(1024) void k_scan1(int* __restrict__ mat,
                                                int* __restrict__ bsum) {
    __shared__ int buf[1024];
    const int tid = threadIdx.x;
    const int i = blockIdx.x * 1024 + tid;
    const int v = (i < LSCAN) ? mat[i] : 0;
    buf[tid] = v;
    __syncthreads();
    for (int d = 1; d < 1024; d <<= 1) {
        int t = (tid >= d) ? buf[tid - d] : 0;
        __syncthreads();
        buf[tid] += t;
        __syncthreads();
    }
    if (i < LSCAN) mat[i] = buf[tid] - v;
    if (tid == 1023) bsum[blockIdx.x] = buf[1023];
}

__global__ __launch_bounds__(1024) void k_scan2(int* __restrict__ bsum) {
    __shared__ int buf[1024];
    const int tid = threadIdx.x;
    const int v = (tid < NBLK_SCAN) ? bsum[tid] : 0;
    buf[tid] = v;
    __syncthreads();
    for (int d = 1; d < 1024; d <<= 1) {
        int t = (tid >= d) ? buf[tid - d] : 0;
        __syncthreads();
        buf[tid] += t;
        __syncthreads();
    }
    if (tid < NBLK_SCAN) bsum[tid] = buf[tid] - v;
}

__global__ __launch_bounds__(1024) void k_scan3(int* __restrict__ mat,
                                                const int* __restrict__ bsum) {
    const int i = blockIdx.x * 1024 + threadIdx.x;
    if (i < LSCAN) mat[i] += bsum[blockIdx.x];
}

// ---------------------------------------------------------------------------
// Fused partition (1024 thr): ONE pass writes BOTH bucket-ordered arrays.
//   partE[p] = v | ((e&63)<<17)      partV[p] = e | ((v&63)<<17)
// ---------------------------------------------------------------------------
__global__ __launch_bounds__(1024) void k_partition2(const int* __restrict__ v_idx,
                                                     const int* __restrict__ e_idx,
                                                     const int* __restrict__ mat,
                                                     unsigned* __restrict__ partE,
                                                     unsigned* __restrict__ partV) {
    __shared__ int curE[NBE];
    __shared__ int curV[NBV];
    const int b = blockIdx.x, tid = threadIdx.x;
    for (int j = tid; j < NBE; j += 1024) curE[j] = mat[j * NB + b];
    for (int j = tid; j < NBV; j += 1024) curV[j] = mat[(NBE + j) * NB + b] - NNZ;
    __syncthreads();
    const int base = b * CHUNK;
    for (int i = tid; i < CHUNK; i += 1024) {
        const int v = v_idx[base + i];
        const int e = e_idx[base + i];
        const int pE = atomicAdd(&curE[e >> 6], 1);
        partE[pE] = (unsigned)v | ((unsigned)(e & 63) << 17);
        const int pV = atomicAdd(&curV[v >> 6], 1);
        partV[pV] = (unsigned)e | ((unsigned)(v & 63) << 17);
    }
}

// ---------------------------------------------------------------------------
// Fused sort+gather, edge side: one block per 64-edge bucket.
// (a) LDS counting sort of the bucket's part-entries (hist/scan/scatter),
// (b) quarter-wave register gather reading indices from LDS (broadcast reads),
// (c) coalesced bf16 row write. No global adj, no offE.
// ---------------------------------------------------------------------------
__global__ __launch_bounds__(1024) void k_sortgatherE(const unsigned* __restrict__ part,
                                                      const int* __restrict__ mat,
                                                      const unsigned short* __restrict__ Xpb,
                                                      const float* __restrict__ degE,
                                                      const float* __restrict__ Wdiag,
                                                      unsigned short* __restrict__ Xeb) {
    __shared__ unsigned sbuf[ECAP_E];       // 24 KB
    __shared__ int hist[64], cur[64], pfx[65];
    const int b = blockIdx.x, tid = threadIdx.x;
    const int base = mat[b * NB];
    const int end  = (b == NBE - 1) ? NNZ : mat[(b + 1) * NB];
    const int nb = end - base;

    if (tid < 64) hist[tid] = 0;
    __syncthreads();
    for (int i = tid; i < nb; i += 1024)
        atomicAdd(&hist[(part[base + i] >> 17) & 63], 1);
    __syncthreads();
    if (tid == 0) {
        int s = 0;
        for (int k = 0; k < 64; ++k) { pfx[k] = s; cur[k] = s; s += hist[k]; }
        pfx[64] = s;
    }
    __syncthreads();
    for (int i = tid; i < nb; i += 1024) {
        const unsigned u = part[base + i];
        const int p = atomicAdd(&cur[(u >> 17) & 63], 1);
        sbuf[p] = u & 0x1FFFFu;
    }
    __syncthreads();

    const int wv = tid >> 6, lane = tid & 63;
    const int q = lane >> 4, sl = lane & 15;
#pragma unroll
    for (int j = 0; j < 4; ++j) {
        const int le = wv * 4 + j;
        const int e_id = (b << 6) + le;
        const int s0 = pfx[le];
        const int n  = pfx[le + 1] - s0;
        float a0 = 0.f, a1 = 0.f, a2 = 0.f, a3 = 0.f;
        const int nf = n >> 2;
        int t = 0;
        for (; t + 4 <= nf; t += 4) {
            int idx[4]; uint2 u4[4];
#pragma unroll
            for (int z = 0; z < 4; ++z) idx[z] = (int)sbuf[s0 + 4 * (t + z) + q];
#pragma unroll
            for (int z = 0; z < 4; ++z)
                u4[z] = *(const uint2*)&Xpb[(size_t)idx[z] * KOUT + 4 * sl];
#pragma unroll
            for (int z = 0; z < 4; ++z) {
                a0 += bf2f_lo(u4[z].x); a1 += bf2f_hi(u4[z].x);
                a2 += bf2f_lo(u4[z].y); a3 += bf2f_hi(u4[z].y);
            }
        }
        for (; t < nf; ++t) {
            const int idx = (int)sbuf[s0 + 4 * t + q];
            const uint2 u = *(const uint2*)&Xpb[(size_t)idx * KOUT + 4 * sl];
            a0 += bf2f_lo(u.x); a1 += bf2f_hi(u.x);
            a2 += bf2f_lo(u.y); a3 += bf2f_hi(u.y);
        }
        if (n & 3) {
            const int src = nf * 4 + q;
            if (src < n) {
                const int idx = (int)sbuf[s0 + src];
                const uint2 u = *(const uint2*)&Xpb[(size_t)idx * KOUT + 4 * sl];
                a0 += bf2f_lo(u.x); a1 += bf2f_hi(u.x);
                a2 += bf2f_lo(u.y); a3 += bf2f_hi(u.y);
            }
        }
        a0 += __shfl_xor(a0, 16, 64); a0 += __shfl_xor(a0, 32, 64);
        a1 += __shfl_xor(a1, 16, 64); a1 += __shfl_xor(a1, 32, 64);
        a2 += __shfl_xor(a2, 16, 64); a2 += __shfl_xor(a2, 32, 64);
        a3 += __shfl_xor(a3, 16, 64); a3 += __shfl_xor(a3, 32, 64);
        if (q == 0 && e_id < NE) {
            const float s = degE[e_id] * Wdiag[e_id];
            uint2 pk;
            pk.x = (unsigned)f2bf(a0 * s) | ((unsigned)f2bf(a1 * s) << 16);
            pk.y = (unsigned)f2bf(a2 * s) | ((unsigned)f2bf(a3 * s) << 16);
            *(uint2*)&Xeb[(size_t)e_id * KOUT + 4 * sl] = pk;
        }
    }
}

// ---------------------------------------------------------------------------
// Fused sort+gather, vertex side: one block per 64-vertex bucket; f32 out.
// ---------------------------------------------------------------------------
__global__ __launch_bounds__(1024) void k_sortgatherV(const unsigned* __restrict__ part,
                                                      const int* __restrict__ mat,
                                                      const unsigned short* __restrict__ Xeb,
                                                      const float* __restrict__ degV,
                                                      float* __restrict__ out) {
    __shared__ unsigned sbuf[ECAP_V];       // 16 KB
    __shared__ int hist[64], cur[64], pfx[65];
    const int b = blockIdx.x, tid = threadIdx.x;
    const int base = mat[NBE * NB + b * NB] - NNZ;
    const int end  = (b == NBV - 1) ? NNZ : (mat[NBE * NB + (b + 1) * NB] - NNZ);
    const int nb = end - base;

    if (tid < 64) hist[tid] = 0;
    __syncthreads();
    for (int i = tid; i < nb; i += 1024)
        atomicAdd(&hist[(part[base + i] >> 17) & 63], 1);
    __syncthreads();
    if (tid == 0) {
        int s = 0;
        for (int k = 0; k < 64; ++k) { pfx[k] = s; cur[k] = s; s += hist[k]; }
        pfx[64] = s;
    }
    __syncthreads();
    for (int i = tid; i < nb; i += 1024) {
        const unsigned u = part[base + i];
        const int p = atomicAdd(&cur[(u >> 17) & 63], 1);
        sbuf[p] = u & 0x1FFFFu;
    }
    __syncthreads();

    const int wv = tid >> 6, lane = tid & 63;
    const int q = lane >> 4, sl = lane & 15;
#pragma unroll
    for (int j = 0; j < 4; ++j) {
        const int lv = wv * 4 + j;
        const int v_id = (b << 6) + lv;
        const int s0 = pfx[lv];
        const int n  = pfx[lv + 1] - s0;
        float a0 = 0.f, a1 = 0.f, a2 = 0.f, a3 = 0.f;
        const int nf = n >> 2;
        int t = 0;
        for (; t + 4 <= nf; t += 4) {
            int idx[4]; uint2 u4[4];
#pragma unroll
            for (int z = 0; z < 4; ++z) idx[z] = (int)sbuf[s0 + 4 * (t + z) + q];
#pragma unroll
            for (int z = 0; z < 4; ++z)
                u4[z] = *(const uint2*)&Xeb[(size_t)idx[z] * KOUT + 4 * sl];
#pragma unroll
            for (int z = 0; z < 4; ++z) {
                a0 += bf2f_lo(u4[z].x); a1 += bf2f_hi(u4[z].x);
                a2 += bf2f_lo(u4[z].y); a3 += bf2f_hi(u4[z].y);
            }
        }
        for (; t < nf; ++t) {
            const int idx = (int)sbuf[s0 + 4 * t + q];
            const uint2 u = *(const uint2*)&Xeb[(size_t)idx * KOUT + 4 * sl];
            a0 += bf2f_lo(u.x); a1 += bf2f_hi(u.x);
            a2 += bf2f_lo(u.y); a3 += bf2f_hi(u.y);
        }
        if (n & 3) {
            const int src = nf * 4 + q;
            if (src < n) {
                const int idx = (int)sbuf[s0 + src];
                const uint2 u = *(const uint2*)&Xeb[(size_t)idx * KOUT + 4 * sl];
                a0 += bf2f_lo(u.x); a1 += bf2f_hi(u.x);
                a2 += bf2f_lo(u.y); a3 += bf2f_hi(u.y);
            }
        }
        a0 += __shfl_xor(a0, 16, 64); a0 += __shfl_xor(a0, 32, 64);
        a1 += __shfl_xor(a1, 16, 64); a1 += __shfl_xor(a1, 32, 64);
        a2 += __shfl_xor(a2, 16, 64); a2 += __shfl_xor(a2, 32, 64);
        a3 += __shfl_xor(a3, 16, 64); a3 += __shfl_xor(a3, 32, 64);
        if (q == 0 && v_id < NV) {
            const float s = degV[v_id];
            *(float4*)&out[(size_t)v_id * KOUT + 4 * sl] =
                make_float4(a0 * s, a1 * s, a2 * s, a3 * s);
        }
    }
}

extern "C" void kernel_launch(void* const* d_in, const int* in_sizes, int n_in,
                              void* d_out, int out_size, void* d_ws, size_t ws_size,
                              hipStream_t stream) {
    const float* X     = (const float*)d_in[0];
    const float* W     = (const float*)d_in[1];
    const float* degE  = (const float*)d_in[2];
    const float* degV  = (const float*)d_in[3];
    const float* Wdiag = (const float*)d_in[4];
    const int*   v_idx = (const int*)d_in[5];
    const int*   e_idx = (const int*)d_in[6];
    float* out = (float*)d_out;

    // Workspace (~46 MB). No adj/off arrays anymore.
    unsigned short* Xpb  = (unsigned short*)d_ws;             // NV*KOUT bf16 (12.8 MB)
    unsigned short* Xeb  = Xpb + (size_t)NV * KOUT;           // NE*KOUT bf16 (6.4 MB)
    unsigned*       partE = (unsigned*)(Xeb + (size_t)NE * KOUT); // NNZ u32
    unsigned*       partV = partE + NNZ;                      // NNZ u32
    int*            mat   = (int*)(partV + NNZ);              // LSCAN
    int*            bsum  = mat + LSCAN;                      // NBLK_SCAN
    unsigned short* Wb    = (unsigned short*)(bsum + ((NBLK_SCAN + 3) & ~3)); // 32 KB

    k_wb<<<(KIN * KOUT) / 256, 256, 0, stream>>>(W, Wb);
    k_project<<<(NV + 127) / 128, 256, 0, stream>>>(X, Wb, Xpb);

    k_hist<<<NB, 1024, 0, stream>>>(v_idx, e_idx, mat);
    k_scan1<<<NBLK_SCAN, 1024, 0, stream>>>(mat, bsum);
    k_scan2<<<1, 1024, 0, stream>>>(bsum);
    k_scan3<<<NBLK_SCAN, 1024, 0, stream>>>(mat, bsum);

    // One fused pass writes both bucket-ordered arrays
    k_partition2<<<NB, 1024, 0, stream>>>(v_idx, e_idx, mat, partE, partV);

    // ---- Fused per-bucket sort + gather (no global CSR round-trip)
    k_sortgatherE<<<NBE, 1024, 0, stream>>>(partE, mat, Xpb, degE, Wdiag, Xeb);
    k_sortgatherV<<<NBV, 1024, 0, stream>>>(partV, mat, Xeb, degV, out);
}